// Round 3
// baseline (329.879 us; speedup 1.0000x reference)
//
#include <hip/hip_runtime.h>
#include <cmath>
#include <cstdint>

// B=64, T=64, W=20, D=1024, K=4, STRIDE=4 ; conv lengths 64->16->4->1 ; T_total=21
// VCb is STACKED: rows [0,1024)=conv0-level (j=r>>4,t=r&15), [1024,1280)=conv1-level
// (j=(r-1024)>>2, t=16+((r-1024)&3)), [1280,1344)=conv2-level (j=r-1280, t=20).

typedef __bf16 bf16_t;
typedef bf16_t bf16x8 __attribute__((ext_vector_type(8)));
typedef bf16_t bf16x4 __attribute__((ext_vector_type(4)));
typedef bf16_t bf16x2 __attribute__((ext_vector_type(2)));
typedef float  f32x4  __attribute__((ext_vector_type(4)));

#define CP0_SL   1048576
#define CP1_SL   262144
#define CP2_SL   65536

#define MFMA16(a,b,c) __builtin_amdgcn_mfma_f32_16x16x32_bf16(a, b, c, 0, 0, 0)

__device__ __forceinline__ void gload_lds16(const void* g, void* l) {
    __builtin_amdgcn_global_load_lds(
        (const __attribute__((address_space(1))) void*)g,
        (__attribute__((address_space(3))) void*)l, 16, 0, 0);
}

// swizzled LDS offset (bf16 units): physical chunk = c ^ (row&7). row stride 64 bf16.
__device__ __forceinline__ int swz(int r, int c) { return (r * 8 + (c ^ (r & 7))) * 8; }

// ---------------- LDS-staged (i,k)->(k,i) weight transpose, 4 o-rows/block ----
// wt[o][k*1024+i] = w[o][i*4+k].  Coalesced reads AND writes.
__device__ __forceinline__ void wtrans4(const float* __restrict__ w,
                                        bf16_t* __restrict__ wt,
                                        int o0, int tid, bf16_t* lds /*16384*/)
{
    #pragma unroll
    for (int oo = 0; oo < 4; oo++) {
        const float* src = w + ((size_t)(o0 + oo) << 12);
        #pragma unroll
        for (int q = 0; q < 2; q++) {
            f32x4 va = *(const f32x4*)(src + tid * 16 + q * 8);      // i = tid*4+2q
            f32x4 vb = *(const f32x4*)(src + tid * 16 + q * 8 + 4);  // i = tid*4+2q+1
            int ib = tid * 4 + 2 * q;
            #pragma unroll
            for (int k = 0; k < 4; k++) {
                bf16x2 p2 = { (bf16_t)va[k], (bf16_t)vb[k] };
                *(bf16x2*)(lds + oo * 4096 + k * 1024 + ib) = p2;
            }
        }
    }
    __syncthreads();
    #pragma unroll
    for (int oo = 0; oo < 4; oo++) {
        bf16x8 v0 = *(bf16x8*)(lds + oo * 4096 + tid * 16);
        bf16x8 v1 = *(bf16x8*)(lds + oo * 4096 + tid * 16 + 8);
        bf16_t* dst = wt + ((size_t)(o0 + oo) << 12) + tid * 16;
        *(bf16x8*)dst       = v0;
        *(bf16x8*)(dst + 8) = v1;
    }
}

// ---------------- wide f32 -> bf16 cast, 8 elems/thread -----------------------
__device__ __forceinline__ void cast8(const float* __restrict__ s,
                                      bf16_t* __restrict__ d, int idx8)
{
    f32x4 a = *(const f32x4*)(s + (size_t)idx8 * 8);
    f32x4 b = *(const f32x4*)(s + (size_t)idx8 * 8 + 4);
    bf16x8 o;
    #pragma unroll
    for (int e = 0; e < 4; e++) { o[e] = (bf16_t)a[e]; o[4 + e] = (bf16_t)b[e]; }
    *(bf16x8*)(d + (size_t)idx8 * 8) = o;
}

// ---------------- shared 64x64 bf16 MFMA NT tile (double-buffered) ------------
// If Dbf: write bf16 Dbf[gm*Nc+cg] = acc + bias[cg]  (splitK=1 fused epilogue).
// Else:   write f32  Cf[gm*Nc+cg] = acc.
__device__ __forceinline__ void gemm64(
    const bf16_t* __restrict__ A, const bf16_t* __restrict__ B,
    int Nc, int K, int m0A, int n0B, int k0, int nIt, int m0C, int n0C,
    bf16_t* sA, bf16_t* sB,
    float* __restrict__ Cf, const float* __restrict__ bias, bf16_t* __restrict__ Dbf)
{
    const int tid  = threadIdx.x;
    const int lane = tid & 63, wave = tid >> 6;
    const int sr = tid >> 3, pc = tid & 7, lc = pc ^ (sr & 7);
    const bf16_t* Ag = A + (size_t)(m0A + sr) * K + k0 + lc * 8;
    const bf16_t* Bg = B + (size_t)(n0B + sr) * K + k0 + lc * 8;
    const size_t rowskip = (size_t)32 * K;
    const int wr = (wave >> 1) * 32, wc = (wave & 1) * 32;
    const int fm = lane & 15, cb = lane >> 4;
    int offA[2][2], offB[2][2];
    #pragma unroll
    for (int h = 0; h < 2; h++) {
        offA[h][0] = swz(wr +      fm, cb + h * 4);
        offA[h][1] = swz(wr + 16 + fm, cb + h * 4);
        offB[h][0] = swz(wc +      fm, cb + h * 4);
        offB[h][1] = swz(wc + 16 + fm, cb + h * 4);
    }
    f32x4 acc[2][2];
    #pragma unroll
    for (int a = 0; a < 2; a++)
        #pragma unroll
        for (int b = 0; b < 2; b++) acc[a][b] = (f32x4){0.f, 0.f, 0.f, 0.f};

    gload_lds16(Ag,           sA + tid * 8);
    gload_lds16(Ag + rowskip, sA + 2048 + tid * 8);
    gload_lds16(Bg,           sB + tid * 8);
    gload_lds16(Bg + rowskip, sB + 2048 + tid * 8);
    for (int it = 0; it < nIt; ++it) {
        const int buf = it & 1;
        const bf16_t* cA = sA + buf * 4096;
        const bf16_t* cB = sB + buf * 4096;
        __syncthreads();
        if (it + 1 < nIt) {
            const bf16_t* a = Ag + (it + 1) * 64;
            const bf16_t* b = Bg + (it + 1) * 64;
            bf16_t* dA = sA + (buf ^ 1) * 4096;
            bf16_t* dB = sB + (buf ^ 1) * 4096;
            gload_lds16(a,           dA + tid * 8);
            gload_lds16(a + rowskip, dA + 2048 + tid * 8);
            gload_lds16(b,           dB + tid * 8);
            gload_lds16(b + rowskip, dB + 2048 + tid * 8);
        }
        #pragma unroll
        for (int h = 0; h < 2; h++) {
            bf16x8 a0 = *(const bf16x8*)&cA[offA[h][0]];
            bf16x8 a1 = *(const bf16x8*)&cA[offA[h][1]];
            bf16x8 b0 = *(const bf16x8*)&cB[offB[h][0]];
            bf16x8 b1 = *(const bf16x8*)&cB[offB[h][1]];
            acc[0][0] = MFMA16(a0, b0, acc[0][0]);
            acc[0][1] = MFMA16(a0, b1, acc[0][1]);
            acc[1][0] = MFMA16(a1, b0, acc[1][0]);
            acc[1][1] = MFMA16(a1, b1, acc[1][1]);
        }
    }
    // C/D layout: col = lane&15, row = (lane>>4)*4 + reg   [verified m89/m91]
    #pragma unroll
    for (int im = 0; im < 2; im++)
        #pragma unroll
        for (int rr = 0; rr < 4; rr++) {
            int gm = m0C + wr + im * 16 + cb * 4 + rr;
            #pragma unroll
            for (int in_ = 0; in_ < 2; in_++) {
                int cg = n0C + wc + in_ * 16 + fm;
                if (Dbf) Dbf[(size_t)gm * Nc + cg] = (bf16_t)(acc[im][in_][rr] + bias[cg]);
                else     Cf[(size_t)gm * Nc + cg] = acc[im][in_][rr];
            }
        }
}

// ---------------- wave-per-row L2 norm of a VCb row ---------------------------
__device__ __forceinline__ void rownorm_row(const bf16_t* __restrict__ VCb,
                                            float* __restrict__ VN, int r, int tid)
{
    const int lane = tid & 63;
    const bf16_t* x = VCb + ((size_t)r << 10) + lane * 16;
    bf16x8 v0 = *(const bf16x8*)x, v1 = *(const bf16x8*)(x + 8);
    float s = 0.f;
    #pragma unroll
    for (int e = 0; e < 8; e++) {
        float a = (float)v0[e], b = (float)v1[e];
        s += a * a + b * b;
    }
    #pragma unroll
    for (int o = 32; o; o >>= 1) s += __shfl_xor(s, o, 64);
    if (lane == 0) VN[r] = sqrtf(s);
}

// ---------------- per-(i, stacked-col) sim (single CPat slice) ----------------
__device__ __forceinline__ void sim_compute(
    int i, int c, const float* __restrict__ CPat, const float* __restrict__ VN,
    const float* Gs, const float* msk, float* __restrict__ SA)
{
    float s[20], p[20];
    float mx = -1e30f;
    #pragma unroll
    for (int w = 0; w < 20; w++) {
        s[w] = CPat[(size_t)(i * 20 + w) * 1344 + c];
        if (msk[w] != 0.f) mx = fmaxf(mx, s[w]);
    }
    float denom = 0.f, num = 0.f;
    #pragma unroll
    for (int w = 0; w < 20; w++) {
        p[w] = (msk[w] != 0.f) ? __expf(s[w] - mx) : 0.f;
        denom += p[w];
        num   += p[w] * s[w];
    }
    float quad = 0.f;
    #pragma unroll
    for (int w = 0; w < 20; w++) {
        float cc = 0.f;
        #pragma unroll
        for (int w2 = 0; w2 < 20; w2++) cc += Gs[w * 20 + w2] * p[w2];
        quad += p[w] * cc;
    }
    float dot = num / denom;
    float vsn = sqrtf(fmaxf(quad, 0.f)) / denom;
    float sim = dot / (fmaxf(VN[c], 1e-8f) * fmaxf(vsn, 1e-8f));
    int j, t;
    if (c < 1024)      { j = c >> 4;          t = c & 15; }
    else if (c < 1280) { j = (c - 1024) >> 2; t = 16 + ((c - 1024) & 3); }
    else               { j = c - 1280;        t = 20; }
    SA[((size_t)i * 64 + j) * 21 + t] = sim;
}

// ================= K1: WT0 LDS-transpose + video cast =========================
__global__ __launch_bounds__(256) void prep0_kernel(
    const float* __restrict__ c0w, bf16_t* __restrict__ WT0,
    const float* __restrict__ video, bf16_t* __restrict__ Vb)
{
    __shared__ __align__(16) bf16_t lds[16384];
    int bx = blockIdx.x;
    if (bx < 256) wtrans4(c0w, WT0, bx * 4, threadIdx.x, lds);
    else          cast8(video, Vb, (bx - 256) * 256 + threadIdx.x);
}

// ===== K2: conv0 128x128 GEMM (splitK x4) || WT1/WT2 transposes || casts ======
__global__ __launch_bounds__(256) void d2_kernel(
    const bf16_t* __restrict__ Vb, const bf16_t* __restrict__ WT0, float* __restrict__ CP0,
    const float* __restrict__ c1w, const float* __restrict__ c2w,
    bf16_t* __restrict__ WT1, bf16_t* __restrict__ WT2,
    const float* __restrict__ words, bf16_t* __restrict__ Wordsb,
    const float* __restrict__ c1dw, bf16_t* __restrict__ C1b,
    const float* __restrict__ fcw, bf16_t* __restrict__ Fb)
{
    __shared__ __align__(16) bf16_t smem[32768];   // 64KB
    const int bx = blockIdx.x, tid = threadIdx.x;
    if (bx < 256) {
        // 128x128 tile, 4 waves of 64x64, BK=64, dbuf; splitK x4 (Kchunk 1024)
        bf16_t* sA = smem;            // 2 x 8192
        bf16_t* sB = smem + 16384;    // 2 x 8192
        const int z = bx >> 6, rem = bx & 63, xt = rem & 7, yt = rem >> 3;
        const int m0 = xt * 128, n0 = yt * 128, k0 = z * 1024;
        const int lane = tid & 63, wave = tid >> 6;
        const int sr = tid >> 3, pc = tid & 7, lc = pc ^ (sr & 7);
        const bf16_t* Ag = Vb  + (size_t)(m0 + sr) * 4096 + k0 + lc * 8;
        const bf16_t* Bg = WT0 + (size_t)(n0 + sr) * 4096 + k0 + lc * 8;
        const size_t rowskip = (size_t)32 * 4096;
        const int wrow = (wave >> 1) * 64, wcol = (wave & 1) * 64;
        const int fm = lane & 15, cb = lane >> 4;
        int offA[2][4], offB[2][4];
        #pragma unroll
        for (int h = 0; h < 2; h++)
            #pragma unroll
            for (int m = 0; m < 4; m++) {
                offA[h][m] = swz(wrow + m * 16 + fm, cb + h * 4);
                offB[h][m] = swz(wcol + m * 16 + fm, cb + h * 4);
            }
        f32x4 acc[4][4];
        #pragma unroll
        for (int m = 0; m < 4; m++)
            #pragma unroll
            for (int n = 0; n < 4; n++) acc[m][n] = (f32x4){0.f, 0.f, 0.f, 0.f};

        #pragma unroll
        for (int g = 0; g < 4; g++) {
            gload_lds16(Ag + g * rowskip, &sA[tid * 8 + g * 2048]);
            gload_lds16(Bg + g * rowskip, &sB[tid * 8 + g * 2048]);
        }
        for (int it = 0; it < 16; ++it) {
            const int buf = it & 1;
            __syncthreads();
            if (it < 15) {
                const bf16_t* a = Ag + (it + 1) * 64;
                const bf16_t* b = Bg + (it + 1) * 64;
                #pragma unroll
                for (int g = 0; g < 4; g++) {
                    gload_lds16(a + g * rowskip, &sA[(buf ^ 1) * 8192 + tid * 8 + g * 2048]);
                    gload_lds16(b + g * rowskip, &sB[(buf ^ 1) * 8192 + tid * 8 + g * 2048]);
                }
            }
            #pragma unroll
            for (int h = 0; h < 2; h++) {
                bf16x8 av[4], bv[4];
                #pragma unroll
                for (int m = 0; m < 4; m++) {
                    av[m] = *(const bf16x8*)&sA[buf * 8192 + offA[h][m]];
                    bv[m] = *(const bf16x8*)&sB[buf * 8192 + offB[h][m]];
                }
                #pragma unroll
                for (int m = 0; m < 4; m++)
                    #pragma unroll
                    for (int n = 0; n < 4; n++)
                        acc[m][n] = MFMA16(av[m], bv[n], acc[m][n]);
            }
        }
        float* Cz = CP0 + (size_t)z * CP0_SL;
        #pragma unroll
        for (int m = 0; m < 4; m++)
            #pragma unroll
            for (int rr = 0; rr < 4; rr++) {
                int gm = m0 + wrow + m * 16 + cb * 4 + rr;
                #pragma unroll
                for (int n = 0; n < 4; n++) {
                    int cg = n0 + wcol + n * 16 + fm;
                    Cz[(size_t)gm * 1024 + cg] = acc[m][n][rr];
                }
            }
    } else if (bx < 768) {                  // WT1/WT2 LDS transposes
        int b2 = bx - 256;
        if (b2 < 256) wtrans4(c1w, WT1, b2 * 4, tid, smem);
        else          wtrans4(c2w, WT2, (b2 - 256) * 4, tid, smem);
    } else {                                // words / conv1d_w / fc_w casts
        int b2 = bx - 768;
        if (b2 < 640)       cast8(words, Wordsb, b2 * 256 + tid);
        else if (b2 < 1152) cast8(c1dw, C1b, (b2 - 640) * 256 + tid);
        else                cast8(fcw, Fb, (b2 - 1152) * 256 + tid);
    }
}

// ============== K3: conv0 epilogue (4 slices, relu) || word gram ==============
__global__ __launch_bounds__(256) void d3_kernel(
    const float* __restrict__ CP0, const float* __restrict__ c0b,
    bf16_t* __restrict__ Astack, const bf16_t* __restrict__ Wordsb,
    float* __restrict__ GR)
{
    __shared__ __align__(16) bf16_t smem[20480];   // 40KB (gram path only)
    int bx = blockIdx.x, tid = threadIdx.x;
    if (bx < 512) {
        int idx8 = bx * 256 + tid;          // < 131072 ; 8 elems each
        size_t base = (size_t)idx8 * 8;
        int nb = (int)(base & 1023);
        f32x4 s0 = *(const f32x4*)(c0b + nb);
        f32x4 s1 = *(const f32x4*)(c0b + nb + 4);
        #pragma unroll
        for (int z = 0; z < 4; z++) {
            const float* p = CP0 + (size_t)z * CP0_SL + base;
            s0 += *(const f32x4*)p;
            s1 += *(const f32x4*)(p + 4);
        }
        bf16x8 o;
        #pragma unroll
        for (int e = 0; e < 4; e++) {
            o[e]     = (bf16_t)fmaxf(s0[e], 0.f);
            o[4 + e] = (bf16_t)fmaxf(s1[e], 0.f);
        }
        *(bf16x8*)(Astack + base) = o;
    } else {
        // gram: one block per i; stage 20 word rows (40KB) then 400 dots
        int i = bx - 512;
        const bf16_t* Wr = Wordsb + (size_t)i * 20480;
        #pragma unroll
        for (int c = 0; c < 10; c++)
            gload_lds16(Wr + (c * 256 + tid) * 8, smem + (c * 256 + tid) * 8);
        __syncthreads();
        int wave = tid >> 6, lane = tid & 63;
        for (int r = 0; r < 100; ++r) {
            int p = wave * 100 + r;
            int w1 = p / 20, w2 = p % 20;
            const bf16_t* a = smem + w1 * 1024 + lane * 16;
            const bf16_t* b = smem + w2 * 1024 + lane * 16;
            bf16x8 a0 = *(const bf16x8*)a, a1 = *(const bf16x8*)(a + 8);
            bf16x8 b0 = *(const bf16x8*)b, b1 = *(const bf16x8*)(b + 8);
            float s = 0.f;
            #pragma unroll
            for (int e = 0; e < 8; e++)
                s += (float)a0[e] * (float)b0[e] + (float)a1[e] * (float)b1[e];
            #pragma unroll
            for (int o = 32; o; o >>= 1) s += __shfl_xor(s, o, 64);
            if (lane == 0) GR[(size_t)i * 400 + p] = s;
        }
    }
}

// ====== K4: conv1 GEMM (splitK x8) || c1d0 -> VCb rows 0..1023 (fused) ========
__global__ __launch_bounds__(256) void d4_kernel(
    const bf16_t* __restrict__ Astack, const bf16_t* __restrict__ WT1,
    const bf16_t* __restrict__ C1b, const float* __restrict__ c1db,
    float* __restrict__ CP1, bf16_t* __restrict__ VCb)
{
    __shared__ __align__(16) bf16_t smem[16384];
    bf16_t* sA = smem; bf16_t* sB = smem + 8192;
    int bx = blockIdx.x;
    if (bx < 512) {          // conv1: M=256 N=1024 K=4096
        int z = bx >> 6, rem = bx & 63, xt = rem & 3, yt = rem >> 2;
        gemm64(Astack, WT1, 1024, 4096, xt * 64, yt * 64, z * 512, 8,
               xt * 64, yt * 64, sA, sB, CP1 + (size_t)z * CP1_SL, nullptr, nullptr);
    } else {                 // c1d0: M=1024 N=1024 K=1024, splitK1 + bias -> bf16
        int b2 = bx - 512;   // 0..255
        int xt = b2 & 15, yt = b2 >> 4;
        gemm64(Astack, C1b, 1024, 1024, xt * 64, yt * 64, 0, 16,
               xt * 64, yt * 64, sA, sB, nullptr, c1db, VCb);
    }
}

// ========= K5: conv1 epi (relu -> A2b) || rownorm rows 0..1023 ================
__global__ __launch_bounds__(256) void d5_kernel(
    const float* __restrict__ CP1, const float* __restrict__ c1b,
    bf16_t* __restrict__ A2b, const bf16_t* __restrict__ VCb, float* __restrict__ VN)
{
    int bx = blockIdx.x, tid = threadIdx.x;
    if (bx < 128) {
        int idx8 = bx * 256 + tid;          // < 32768
        size_t base = (size_t)idx8 * 8;
        int nb = (int)(base & 1023);
        f32x4 s0 = *(const f32x4*)(c1b + nb);
        f32x4 s1 = *(const f32x4*)(c1b + nb + 4);
        #pragma unroll
        for (int z = 0; z < 8; z++) {
            const float* p = CP1 + (size_t)z * CP1_SL + base;
            s0 += *(const f32x4*)p;
            s1 += *(const f32x4*)(p + 4);
        }
        bf16x8 o;
        #pragma unroll
        for (int e = 0; e < 4; e++) {
            o[e]     = (bf16_t)fmaxf(s0[e], 0.f);
            o[4 + e] = (bf16_t)fmaxf(s1[e], 0.f);
        }
        *(bf16x8*)(A2b + base) = o;
    } else {
        int r = (bx - 128) * 4 + (tid >> 6);
        rownorm_row(VCb, VN, r, tid);
    }
}

// == K6: conv2 (splitK x8) || c1d1 -> VCb rows 1024..1279 || attn cols<1024 ====
__global__ __launch_bounds__(256) void d6_kernel(
    const bf16_t* __restrict__ A2b, const bf16_t* __restrict__ WT2,
    const bf16_t* __restrict__ C1b, const float* __restrict__ c1db,
    const bf16_t* __restrict__ Wordsb, bf16_t* __restrict__ VCb,
    float* __restrict__ CP2, float* __restrict__ CPat)
{
    __shared__ __align__(16) bf16_t smem[16384];
    bf16_t* sA = smem; bf16_t* sB = smem + 8192;
    int bx = blockIdx.x;
    if (bx < 128) {          // conv2: M=64 N=1024 K=4096
        int z = bx >> 4, yt = bx & 15;
        gemm64(A2b, WT2, 1024, 4096, 0, yt * 64, z * 512, 8,
               0, yt * 64, sA, sB, CP2 + (size_t)z * CP2_SL, nullptr, nullptr);
    } else if (bx < 192) {   // c1d1: M=256 N=1024 K=1024, splitK1 -> VCb
        int g = bx - 128;
        int xt = g & 3, yt = g >> 2;
        gemm64(A2b, C1b, 1024, 1024, xt * 64, yt * 64, 0, 16,
               1024 + xt * 64, yt * 64, sA, sB, nullptr, c1db, VCb);
    } else {                 // attn0: M=1280, cols 0..1023, K=1024, splitK1
        int g = bx - 192;                   // 0..319
        int xt = g % 20, yt = g / 20;
        gemm64(Wordsb, VCb, 1344, 1024, xt * 64, yt * 64, 0, 16,
               xt * 64, yt * 64, sA, sB, CPat, nullptr, nullptr);
    }
}

// == K7: c1d2+fc fused (conv2-epi in LDS, splitK1 -> VCb/GV) || sim0 || rn-mid
//        || attn cols 1024..1279 =================================================
__global__ __launch_bounds__(256) void d7_kernel(
    const float* __restrict__ CP2, const float* __restrict__ c2b,
    const bf16_t* __restrict__ C1b, const bf16_t* __restrict__ Fb,
    const float* __restrict__ c1db, const float* __restrict__ fcb,
    bf16_t* __restrict__ VCb, float* __restrict__ GV,
    const bf16_t* __restrict__ Wordsb, float* __restrict__ CPat,
    const float* __restrict__ GR, float* __restrict__ VN,
    const int* __restrict__ wmask, float* __restrict__ SA)
{
    __shared__ __align__(16) bf16_t smem[24576];   // 48KB
    const int bx = blockIdx.x, tid = threadIdx.x;
    if (bx < 32) {
        // A = relu(sum_z CP2 + conv2_b) staged per-256-K-chunk into swizzled LDS;
        // full K=1024 per block (splitK1) -> direct bf16/f32 write with bias.
        bf16_t* Abig = smem;                 // 16384 bf16
        bf16_t* sB   = smem + 16384;         // 2 x 4096
        const int which = bx >> 4, yt = bx & 15;
        const int n0 = yt * 64;
        const bf16_t* Bmat = which ? Fb : C1b;
        const int lane = tid & 63, wave = tid >> 6;
        const int sr = tid >> 3, pc = tid & 7, lcx = pc ^ (sr & 7);
        const size_t rowskip = (size_t)32 * 1024;
        const int wr = (wave >> 1) * 32, wc = (wave & 1) * 32;
        const int fm = lane & 15, cb = lane >> 4;
        int aoff[2][2], offB[2][2];
        #pragma unroll
        for (int h = 0; h < 2; h++) {
            int r0 = wr + fm, r1 = wr + 16 + fm;
            aoff[h][0] = r0 * 256 + (((cb + 4 * h) ^ (r0 & 7)) << 3);
            aoff[h][1] = r1 * 256 + (((cb + 4 * h) ^ (r1 & 7)) << 3);
            offB[h][0] = swz(wc +      fm, cb + h * 4);
            offB[h][1] = swz(wc + 16 + fm, cb + h * 4);
        }
        f32x4 acc[2][2];
        #pragma unroll
        for (int a = 0; a < 2; a++)
            #pragma unroll
            for (int b = 0; b < 2; b++) acc[a][b] = (f32x4){0.f, 0.f, 0.f, 0.f};

        for (int zc = 0; zc < 4; zc++) {
            const int k0 = zc * 256;
            __syncthreads();                 // prior MFMA reads of Abig/sB done
            // stage Abig (64 x 256) = relu(sum of 8 CP2 slices + bias)
            #pragma unroll
            for (int qq = 0; qq < 8; qq++) {
                int q = qq * 256 + tid;      // 64 rows x 32 chunks
                int r = q >> 5, ch = q & 31;
                int col = k0 + ch * 8;
                f32x4 s0 = *(const f32x4*)(c2b + col);
                f32x4 s1 = *(const f32x4*)(c2b + col + 4);
                #pragma unroll
                for (int zz = 0; zz < 8; zz++) {
                    const float* p = CP2 + (size_t)zz * CP2_SL + r * 1024 + col;
                    s0 += *(const f32x4*)p;
                    s1 += *(const f32x4*)(p + 4);
                }
                bf16x8 o;
                #pragma unroll
                for (int e = 0; e < 4; e++) {
                    o[e]     = (bf16_t)fmaxf(s0[e], 0.f);
                    o[4 + e] = (bf16_t)fmaxf(s1[e], 0.f);
                }
                *(bf16x8*)(Abig + r * 256 + ((ch ^ (r & 7)) << 3)) = o;
            }
            const bf16_t* Bg = Bmat + (size_t)(n0 + sr) * 1024 + k0 + lcx * 8;
            gload_lds16(Bg,           sB + tid * 8);
            gload_lds16(Bg + rowskip, sB + 2048 + tid * 8);
            for (int it = 0; it < 4; ++it) {
                const int buf = it & 1;
                const bf16_t* cB = sB + buf * 4096;
                __syncthreads();
                if (it < 3) {
                    const bf16_t* b = Bg + (it + 1) * 64;
                    bf16_t* dB = sB + (buf ^ 1) * 4096;
                    gload_lds16(b,           dB + tid * 8);
                    gload_lds16(b + rowskip, dB + 2048 + tid * 8);
                }
                #pragma unroll
                for (int h = 0; h < 2; h++) {
                    bf16x8 a0 = *(const bf16x8*)&Abig[aoff[h][0] + it * 64];
                    bf16x8 a1 = *(const bf16x8*)&Abig[aoff[h][1] + it * 64];
                    bf16x8 b0 = *(const bf16x8*)&cB[offB[h][0]];
                    bf16x8 b1 = *(const bf16x8*)&cB[offB[h][1]];
                    acc[0][0] = MFMA16(a0, b0, acc[0][0]);
                    acc[0][1] = MFMA16(a0, b1, acc[0][1]);
                    acc[1][0] = MFMA16(a1, b0, acc[1][0]);
                    acc[1][1] = MFMA16(a1, b1, acc[1][1]);
                }
            }
        }
        #pragma unroll
        for (int im = 0; im < 2; im++)
            #pragma unroll
            for (int rr = 0; rr < 4; rr++) {
                int gm = wr + im * 16 + cb * 4 + rr;
                #pragma unroll
                for (int in_ = 0; in_ < 2; in_++) {
                    int cg = n0 + wc + in_ * 16 + fm;
                    float v = acc[im][in_][rr];
                    if (which) GV[(size_t)gm * 1024 + cg] = v + fcb[cg];
                    else VCb[(size_t)(1280 + gm) * 1024 + cg] = (bf16_t)(v + c1db[cg]);
                }
            }
    } else if (bx < 288) {   // sim for stacked cols 0..1023
        int s = bx - 32;                    // 0..255
        int i = s >> 2, seg = s & 3;
        float* Gs  = (float*)smem;
        float* msk = Gs + 400;
        for (int q = tid; q < 400; q += 256) Gs[q] = GR[(size_t)i * 400 + q];
        if (tid < 20) msk[tid] = (wmask[i * 20 + tid] != 0) ? 1.f : 0.f;
        __syncthreads();
        sim_compute(i, seg * 256 + tid, CPat, VN, Gs, msk, SA);
    } else if (bx < 352) {   // rownorm rows 1024..1279
        int r = 1024 + (bx - 288) * 4 + (tid >> 6);
        rownorm_row(VCb, VN, r, tid);
    } else {                 // attn1: cols 1024..1279
        int g = bx - 352;                   // 0..79
        int xt = g % 20, yt = g / 20;
        bf16_t* sA = smem; bf16_t* sB = smem + 8192;
        gemm64(Wordsb, VCb, 1344, 1024, xt * 64, 1024 + yt * 64, 0, 16,
               xt * 64, 1024 + yt * 64, sA, sB, CPat, nullptr, nullptr);
    }
}

// = K8: attn cols 1280.. || rownorm 1280.. || gscore || sim cols 1024..1279 ====
__global__ __launch_bounds__(256) void d8_kernel(
    const bf16_t* __restrict__ Wordsb, const bf16_t* __restrict__ VCb,
    float* __restrict__ CPat, float* __restrict__ VN,
    const float* __restrict__ sent, const float* __restrict__ GV,
    float* __restrict__ GS, const float* __restrict__ GR,
    const int* __restrict__ wmask, float* __restrict__ SA)
{
    __shared__ __align__(16) bf16_t smem[16384];
    bf16_t* sA = smem; bf16_t* sB = smem + 8192;
    int bx = blockIdx.x, tid = threadIdx.x;
    if (bx < 20) {           // attn2
        gemm64(Wordsb, VCb, 1344, 1024, bx * 64, 1280, 0, 16,
               bx * 64, 1280, sA, sB, CPat, nullptr, nullptr);
    } else if (bx < 36) {    // rownorm rows 1280..1343
        int r = 1280 + (bx - 20) * 4 + (tid >> 6);
        rownorm_row(VCb, VN, r, tid);
    } else if (bx < 1060) {  // gscore (cosine of sentences vs GV)
        int item = (bx - 36) * 4 + (tid >> 6);
        int i = item >> 6, j = item & 63;
        int lane = tid & 63;
        const float* a = sent + (size_t)i * 1024;
        const float* b = GV + (size_t)j * 1024;
        float sab = 0.f, saa = 0.f, sbb = 0.f;
        #pragma unroll
        for (int q = 0; q < 16; q++) {
            int d = lane + 64 * q;
            float av = a[d], bv = b[d];
            sab += av * bv; saa += av * av; sbb += bv * bv;
        }
        #pragma unroll
        for (int o = 32; o; o >>= 1) {
            sab += __shfl_xor(sab, o, 64);
            saa += __shfl_xor(saa, o, 64);
            sbb += __shfl_xor(sbb, o, 64);
        }
        if (lane == 0)
            GS[item] = sab / (fmaxf(sqrtf(saa), 1e-8f) * fmaxf(sqrtf(sbb), 1e-8f));
    } else {                 // sim cols 1024..1279
        int i = bx - 1060;
        float* Gs  = (float*)smem;
        float* msk = Gs + 400;
        for (int q = tid; q < 400; q += 256) Gs[q] = GR[(size_t)i * 400 + q];
        if (tid < 20) msk[tid] = (wmask[i * 20 + tid] != 0) ? 1.f : 0.f;
        __syncthreads();
        sim_compute(i, 1024 + tid, CPat, VN, Gs, msk, SA);
    }
}

// ================= K9: sim cols 1280..1343 ====================================
__global__ __launch_bounds__(256) void d9_kernel(
    const float* __restrict__ CPat, const float* __restrict__ GR,
    const float* __restrict__ VN, const int* __restrict__ wmask,
    float* __restrict__ SA)
{
    __shared__ float Gs[400];
    __shared__ float msk[20];
    int i = blockIdx.x, tid = threadIdx.x;
    for (int q = tid; q < 400; q += 256) Gs[q] = GR[(size_t)i * 400 + q];
    if (tid < 20) msk[tid] = (wmask[i * 20 + tid] != 0) ? 1.f : 0.f;
    __syncthreads();
    if (tid < 64) sim_compute(i, 1280 + tid, CPat, VN, Gs, msk, SA);
}

// ================= K10: scores + positive_map =================================
__global__ __launch_bounds__(256) void d10_kernel(
    const float* __restrict__ SA, float* __restrict__ SC, float* __restrict__ out)
{
    int idx = blockIdx.x * 256 + threadIdx.x;   // 4096
    int i = idx >> 6, j = idx & 63;
    const float* row = SA + (size_t)idx * 21;
    float s = 0.f;
    #pragma unroll
    for (int t = 0; t < 21; t++) s += row[t];
    SC[idx] = s * (1.0f / 21.0f);
    if (i == j) {
        #pragma unroll
        for (int t = 0; t < 21; t++) out[1 + i * 21 + t] = row[t];
    }
}

// ================= K11: margin ranking loss ===================================
__global__ __launch_bounds__(256) void loss_kernel(
    const float* __restrict__ SC_, const float* __restrict__ GS_,
    float* __restrict__ out)
{
    __shared__ float d1[64], d2[64], red[4];
    int tid = threadIdx.x;
    if (tid < 64) { d1[tid] = SC_[tid * 65]; d2[tid] = GS_[tid * 65]; }
    __syncthreads();
    float acc = 0.f;
    for (int idx = tid; idx < 4096; idx += 256) {
        int i = idx >> 6, j = idx & 63;
        if (i != j) {
            float s = SC_[idx];
            acc += fmaxf(0.2f + s - d1[i], 0.f) + fmaxf(0.2f + s - d1[j], 0.f);
            float g = GS_[idx];
            acc += fmaxf(0.2f + g - d2[i], 0.f) + fmaxf(0.2f + g - d2[j], 0.f);
        }
    }
    #pragma unroll
    for (int o = 32; o; o >>= 1) acc += __shfl_xor(acc, o, 64);
    if ((tid & 63) == 0) red[tid >> 6] = acc;
    __syncthreads();
    if (tid == 0) out[0] = (red[0] + red[1] + red[2] + red[3]) * (1.0f / 64.0f);
}

// ------------------------------------------------------------------------------
extern "C" void kernel_launch(void* const* d_in, const int* in_sizes, int n_in,
                              void* d_out, int out_size, void* d_ws, size_t ws_size,
                              hipStream_t stream)
{
    const float* video     = (const float*)d_in[0];
    const float* words     = (const float*)d_in[1];
    const int*   w_masks   = (const int*)  d_in[2];
    const float* sentences = (const float*)d_in[3];
    const float* conv0_w   = (const float*)d_in[4];
    const float* conv0_b   = (const float*)d_in[5];
    const float* conv1_w   = (const float*)d_in[6];
    const float* conv1_b   = (const float*)d_in[7];
    const float* conv2_w   = (const float*)d_in[8];
    const float* conv2_b   = (const float*)d_in[9];
    const float* conv1d_w  = (const float*)d_in[10];
    const float* conv1d_b  = (const float*)d_in[11];
    const float* fc_w      = (const float*)d_in[12];
    const float* fc_b      = (const float*)d_in[13];
    float* out = (float*)d_out;
    float* ws = (float*)d_ws;

    // ---- flat workspace (float units) ----------------------------------------
    bf16_t* WT0    = (bf16_t*)(ws + 0);            // 1024x4096 bf16
    bf16_t* WT1    = (bf16_t*)(ws + 2097152);
    bf16_t* WT2    = (bf16_t*)(ws + 4194304);
    bf16_t* Vb     = (bf16_t*)(ws + 6291456);      // 4096x1024 bf16
    bf16_t* Wordsb = (bf16_t*)(ws + 8388608);      // 1,310,720 bf16
    bf16_t* C1b    = (bf16_t*)(ws + 9043968);      // 1,048,576 bf16
    bf16_t* Fb     = (bf16_t*)(ws + 9568256);      // 1,048,576 bf16
    bf16_t* Astack = (bf16_t*)(ws + 10092544);     // 1024x1024 bf16 (conv0 out)
    bf16_t* A2b    = (bf16_t*)(ws + 10616832);     // 256x1024 bf16 (conv1 out)
    bf16_t* VCb    = (bf16_t*)(ws + 10747904);     // 1344x1024 bf16 (STACKED)
    float*  CP0    = ws + 11436032;                // 4 x 1,048,576 f
    float*  CP1    = ws + 15630336;                // 8 x 262,144 f
    float*  CP2    = ws + 17727488;                // 8 x 65,536 f
    float*  CPat   = ws + 18251776;                // 1,720,320 f (single slice)
    float*  VN     = ws + 19972096;                // 1,344
    float*  GR     = ws + 19973440;                // 25,600
    float*  SA     = ws + 19999040;                // 86,016
    float*  SC     = ws + 20085056;                // 4,096
    float*  GV     = ws + 20089152;                // 65,536
    float*  GS     = ws + 20154688;                // 4,096 (ends 20,158,784)

    dim3 blk(256);

    // K1: WT0 transpose + video cast
    prep0_kernel<<<2304, blk, 0, stream>>>(conv0_w, WT0, video, Vb);
    // K2: conv0 GEMM || WT1/WT2 transposes || casts
    d2_kernel<<<2432, blk, 0, stream>>>(Vb, WT0, CP0, conv1_w, conv2_w, WT1, WT2,
                                        words, Wordsb, conv1d_w, C1b, fc_w, Fb);
    // K3: conv0 epi || gram
    d3_kernel<<<576, blk, 0, stream>>>(CP0, conv0_b, Astack, Wordsb, GR);
    // K4: conv1 GEMM || c1d0 -> VCb[0..1024)
    d4_kernel<<<768, blk, 0, stream>>>(Astack, WT1, C1b, conv1d_b, CP1, VCb);
    // K5: conv1 epi || rownorm rows 0..1023
    d5_kernel<<<384, blk, 0, stream>>>(CP1, conv1_b, A2b, VCb, VN);
    // K6: conv2 || c1d1 -> VCb[1024..1280) || attn cols<1024
    d6_kernel<<<512, blk, 0, stream>>>(A2b, WT2, C1b, conv1d_b, Wordsb, VCb, CP2, CPat);
    // K7: c1d2+fc fused -> VCb[1280..)/GV || sim0 || rownorm-mid || attn1
    d7_kernel<<<432, blk, 0, stream>>>(CP2, conv2_b, C1b, Fb, conv1d_b, fc_b,
                                       VCb, GV, Wordsb, CPat, GR, VN, w_masks, SA);
    // K8: attn2 || rownorm-hi || gscore || sim-mid
    d8_kernel<<<1124, blk, 0, stream>>>(Wordsb, VCb, CPat, VN, sentences, GV, GS,
                                        GR, w_masks, SA);
    // K9-K11: sim tail, scores+posmap, loss
    d9_kernel<<<64, blk, 0, stream>>>(CPat, GR, VN, w_masks, SA);
    d10_kernel<<<16, blk, 0, stream>>>(SA, SC, out);
    loss_kernel<<<1, blk, 0, stream>>>(SC, GS, out);
}

// Round 4
// 291.481 us; speedup vs baseline: 1.1317x; 1.1317x over previous
//
#include <hip/hip_runtime.h>
#include <cmath>
#include <cstdint>

// B=64, T=64, W=20, D=1024, K=4, STRIDE=4 ; conv lengths 64->16->4->1 ; T_total=21
// VCb is STACKED: rows [0,1024)=conv0-level (j=r>>4,t=r&15), [1024,1280)=conv1-level
// (j=(r-1024)>>2, t=16+((r-1024)&3)), [1280,1344)=conv2-level (j=r-1280, t=20).

typedef __bf16 bf16_t;
typedef bf16_t bf16x8 __attribute__((ext_vector_type(8)));
typedef bf16_t bf16x4 __attribute__((ext_vector_type(4)));
typedef bf16_t bf16x2 __attribute__((ext_vector_type(2)));
typedef float  f32x4  __attribute__((ext_vector_type(4)));

#define CP0_SL   1048576

#define MFMA16(a,b,c) __builtin_amdgcn_mfma_f32_16x16x32_bf16(a, b, c, 0, 0, 0)

__device__ __forceinline__ void gload_lds16(const void* g, void* l) {
    __builtin_amdgcn_global_load_lds(
        (const __attribute__((address_space(1))) void*)g,
        (__attribute__((address_space(3))) void*)l, 16, 0, 0);
}

// swizzled LDS offset (bf16 units): physical chunk = c ^ (row&7). row stride 64 bf16.
__device__ __forceinline__ int swz(int r, int c) { return (r * 8 + (c ^ (r & 7))) * 8; }

// ---------------- LDS-staged (i,k)->(k,i) weight transpose, 4 o-rows/block ----
// wt[o][k*1024+i] = w[o][i*4+k].  Coalesced reads AND writes.
__device__ __forceinline__ void wtrans4(const float* __restrict__ w,
                                        bf16_t* __restrict__ wt,
                                        int o0, int tid, bf16_t* lds /*16384*/)
{
    #pragma unroll
    for (int oo = 0; oo < 4; oo++) {
        const float* src = w + ((size_t)(o0 + oo) << 12);
        #pragma unroll
        for (int q = 0; q < 2; q++) {
            f32x4 va = *(const f32x4*)(src + tid * 16 + q * 8);      // i = tid*4+2q
            f32x4 vb = *(const f32x4*)(src + tid * 16 + q * 8 + 4);  // i = tid*4+2q+1
            int ib = tid * 4 + 2 * q;
            #pragma unroll
            for (int k = 0; k < 4; k++) {
                bf16x2 p2 = { (bf16_t)va[k], (bf16_t)vb[k] };
                *(bf16x2*)(lds + oo * 4096 + k * 1024 + ib) = p2;
            }
        }
    }
    __syncthreads();
    #pragma unroll
    for (int oo = 0; oo < 4; oo++) {
        bf16x8 v0 = *(bf16x8*)(lds + oo * 4096 + tid * 16);
        bf16x8 v1 = *(bf16x8*)(lds + oo * 4096 + tid * 16 + 8);
        bf16_t* dst = wt + ((size_t)(o0 + oo) << 12) + tid * 16;
        *(bf16x8*)dst       = v0;
        *(bf16x8*)(dst + 8) = v1;
    }
}

// ---------------- wide f32 -> bf16 cast, 8 elems/thread -----------------------
__device__ __forceinline__ void cast8(const float* __restrict__ s,
                                      bf16_t* __restrict__ d, int idx8)
{
    f32x4 a = *(const f32x4*)(s + (size_t)idx8 * 8);
    f32x4 b = *(const f32x4*)(s + (size_t)idx8 * 8 + 4);
    bf16x8 o;
    #pragma unroll
    for (int e = 0; e < 4; e++) { o[e] = (bf16_t)a[e]; o[4 + e] = (bf16_t)b[e]; }
    *(bf16x8*)(d + (size_t)idx8 * 8) = o;
}

// ---------------- shared 64x64 bf16 MFMA NT tile (double-buffered) ------------
// Output: v = acc (+bias[cg] if bias) (relu if relu); Dbf ? bf16 : f32.
__device__ __forceinline__ void gemm64(
    const bf16_t* __restrict__ A, const bf16_t* __restrict__ B,
    int Nc, int K, int m0A, int n0B, int k0, int nIt, int m0C, int n0C,
    bf16_t* sA, bf16_t* sB,
    float* __restrict__ Cf, const float* __restrict__ bias, bf16_t* __restrict__ Dbf,
    int relu)
{
    const int tid  = threadIdx.x;
    const int lane = tid & 63, wave = tid >> 6;
    const int sr = tid >> 3, pc = tid & 7, lc = pc ^ (sr & 7);
    const bf16_t* Ag = A + (size_t)(m0A + sr) * K + k0 + lc * 8;
    const bf16_t* Bg = B + (size_t)(n0B + sr) * K + k0 + lc * 8;
    const size_t rowskip = (size_t)32 * K;
    const int wr = (wave >> 1) * 32, wc = (wave & 1) * 32;
    const int fm = lane & 15, cb = lane >> 4;
    int offA[2][2], offB[2][2];
    #pragma unroll
    for (int h = 0; h < 2; h++) {
        offA[h][0] = swz(wr +      fm, cb + h * 4);
        offA[h][1] = swz(wr + 16 + fm, cb + h * 4);
        offB[h][0] = swz(wc +      fm, cb + h * 4);
        offB[h][1] = swz(wc + 16 + fm, cb + h * 4);
    }
    f32x4 acc[2][2];
    #pragma unroll
    for (int a = 0; a < 2; a++)
        #pragma unroll
        for (int b = 0; b < 2; b++) acc[a][b] = (f32x4){0.f, 0.f, 0.f, 0.f};

    gload_lds16(Ag,           sA + tid * 8);
    gload_lds16(Ag + rowskip, sA + 2048 + tid * 8);
    gload_lds16(Bg,           sB + tid * 8);
    gload_lds16(Bg + rowskip, sB + 2048 + tid * 8);
    for (int it = 0; it < nIt; ++it) {
        const int buf = it & 1;
        const bf16_t* cA = sA + buf * 4096;
        const bf16_t* cB = sB + buf * 4096;
        __syncthreads();
        if (it + 1 < nIt) {
            const bf16_t* a = Ag + (it + 1) * 64;
            const bf16_t* b = Bg + (it + 1) * 64;
            bf16_t* dA = sA + (buf ^ 1) * 4096;
            bf16_t* dB = sB + (buf ^ 1) * 4096;
            gload_lds16(a,           dA + tid * 8);
            gload_lds16(a + rowskip, dA + 2048 + tid * 8);
            gload_lds16(b,           dB + tid * 8);
            gload_lds16(b + rowskip, dB + 2048 + tid * 8);
        }
        #pragma unroll
        for (int h = 0; h < 2; h++) {
            bf16x8 a0 = *(const bf16x8*)&cA[offA[h][0]];
            bf16x8 a1 = *(const bf16x8*)&cA[offA[h][1]];
            bf16x8 b0 = *(const bf16x8*)&cB[offB[h][0]];
            bf16x8 b1 = *(const bf16x8*)&cB[offB[h][1]];
            acc[0][0] = MFMA16(a0, b0, acc[0][0]);
            acc[0][1] = MFMA16(a0, b1, acc[0][1]);
            acc[1][0] = MFMA16(a1, b0, acc[1][0]);
            acc[1][1] = MFMA16(a1, b1, acc[1][1]);
        }
    }
    // C/D layout: col = lane&15, row = (lane>>4)*4 + reg   [verified m89/m91]
    #pragma unroll
    for (int im = 0; im < 2; im++)
        #pragma unroll
        for (int rr = 0; rr < 4; rr++) {
            int gm = m0C + wr + im * 16 + cb * 4 + rr;
            #pragma unroll
            for (int in_ = 0; in_ < 2; in_++) {
                int cg = n0C + wc + in_ * 16 + fm;
                float v = acc[im][in_][rr];
                if (bias) v += bias[cg];
                if (relu) v = fmaxf(v, 0.f);
                if (Dbf) Dbf[(size_t)gm * Nc + cg] = (bf16_t)v;
                else     Cf[(size_t)gm * Nc + cg] = v;
            }
        }
}

// ---------------- wave-per-row L2 norm of a VCb row ---------------------------
__device__ __forceinline__ void rownorm_row(const bf16_t* __restrict__ VCb,
                                            float* __restrict__ VN, int r, int tid)
{
    const int lane = tid & 63;
    const bf16_t* x = VCb + ((size_t)r << 10) + lane * 16;
    bf16x8 v0 = *(const bf16x8*)x, v1 = *(const bf16x8*)(x + 8);
    float s = 0.f;
    #pragma unroll
    for (int e = 0; e < 8; e++) {
        float a = (float)v0[e], b = (float)v1[e];
        s += a * a + b * b;
    }
    #pragma unroll
    for (int o = 32; o; o >>= 1) s += __shfl_xor(s, o, 64);
    if (lane == 0) VN[r] = sqrtf(s);
}

// ---------------- per-(i, stacked-col) sim (single CPat slice) ----------------
__device__ __forceinline__ void sim_compute(
    int i, int c, const float* __restrict__ CPat, const float* __restrict__ VN,
    const float* Gs, const float* msk, float* __restrict__ SA)
{
    float s[20], p[20];
    float mx = -1e30f;
    #pragma unroll
    for (int w = 0; w < 20; w++) {
        s[w] = CPat[(size_t)(i * 20 + w) * 1344 + c];
        if (msk[w] != 0.f) mx = fmaxf(mx, s[w]);
    }
    float denom = 0.f, num = 0.f;
    #pragma unroll
    for (int w = 0; w < 20; w++) {
        p[w] = (msk[w] != 0.f) ? __expf(s[w] - mx) : 0.f;
        denom += p[w];
        num   += p[w] * s[w];
    }
    float quad = 0.f;
    #pragma unroll
    for (int w = 0; w < 20; w++) {
        float cc = 0.f;
        #pragma unroll
        for (int w2 = 0; w2 < 20; w2++) cc += Gs[w * 20 + w2] * p[w2];
        quad += p[w] * cc;
    }
    float dot = num / denom;
    float vsn = sqrtf(fmaxf(quad, 0.f)) / denom;
    float sim = dot / (fmaxf(VN[c], 1e-8f) * fmaxf(vsn, 1e-8f));
    int j, t;
    if (c < 1024)      { j = c >> 4;          t = c & 15; }
    else if (c < 1280) { j = (c - 1024) >> 2; t = 16 + ((c - 1024) & 3); }
    else               { j = c - 1280;        t = 20; }
    SA[((size_t)i * 64 + j) * 21 + t] = sim;
}

// ================= K1: WT0 LDS-transpose + video cast =========================
__global__ __launch_bounds__(256) void prep0_kernel(
    const float* __restrict__ c0w, bf16_t* __restrict__ WT0,
    const float* __restrict__ video, bf16_t* __restrict__ Vb)
{
    __shared__ __align__(16) bf16_t lds[16384];
    int bx = blockIdx.x;
    if (bx < 256) wtrans4(c0w, WT0, bx * 4, threadIdx.x, lds);
    else          cast8(video, Vb, (bx - 256) * 256 + threadIdx.x);
}

// ===== K2: conv0 128x128 GEMM (splitK x4) || WT1/WT2 transposes || casts ======
__global__ __launch_bounds__(256) void d2_kernel(
    const bf16_t* __restrict__ Vb, const bf16_t* __restrict__ WT0, float* __restrict__ CP0,
    const float* __restrict__ c1w, const float* __restrict__ c2w,
    bf16_t* __restrict__ WT1, bf16_t* __restrict__ WT2,
    const float* __restrict__ words, bf16_t* __restrict__ Wordsb,
    const float* __restrict__ c1dw, bf16_t* __restrict__ C1b,
    const float* __restrict__ fcw, bf16_t* __restrict__ Fb)
{
    __shared__ __align__(16) bf16_t smem[32768];   // 64KB
    const int bx = blockIdx.x, tid = threadIdx.x;
    if (bx < 256) {
        // 128x128 tile, 4 waves of 64x64, BK=64, dbuf; splitK x4 (Kchunk 1024)
        bf16_t* sA = smem;            // 2 x 8192
        bf16_t* sB = smem + 16384;    // 2 x 8192
        const int z = bx >> 6, rem = bx & 63, xt = rem & 7, yt = rem >> 3;
        const int m0 = xt * 128, n0 = yt * 128, k0 = z * 1024;
        const int lane = tid & 63, wave = tid >> 6;
        const int sr = tid >> 3, pc = tid & 7, lc = pc ^ (sr & 7);
        const bf16_t* Ag = Vb  + (size_t)(m0 + sr) * 4096 + k0 + lc * 8;
        const bf16_t* Bg = WT0 + (size_t)(n0 + sr) * 4096 + k0 + lc * 8;
        const size_t rowskip = (size_t)32 * 4096;
        const int wrow = (wave >> 1) * 64, wcol = (wave & 1) * 64;
        const int fm = lane & 15, cb = lane >> 4;
        int offA[2][4], offB[2][4];
        #pragma unroll
        for (int h = 0; h < 2; h++)
            #pragma unroll
            for (int m = 0; m < 4; m++) {
                offA[h][m] = swz(wrow + m * 16 + fm, cb + h * 4);
                offB[h][m] = swz(wcol + m * 16 + fm, cb + h * 4);
            }
        f32x4 acc[4][4];
        #pragma unroll
        for (int m = 0; m < 4; m++)
            #pragma unroll
            for (int n = 0; n < 4; n++) acc[m][n] = (f32x4){0.f, 0.f, 0.f, 0.f};

        #pragma unroll
        for (int g = 0; g < 4; g++) {
            gload_lds16(Ag + g * rowskip, &sA[tid * 8 + g * 2048]);
            gload_lds16(Bg + g * rowskip, &sB[tid * 8 + g * 2048]);
        }
        for (int it = 0; it < 16; ++it) {
            const int buf = it & 1;
            __syncthreads();
            if (it < 15) {
                const bf16_t* a = Ag + (it + 1) * 64;
                const bf16_t* b = Bg + (it + 1) * 64;
                #pragma unroll
                for (int g = 0; g < 4; g++) {
                    gload_lds16(a + g * rowskip, &sA[(buf ^ 1) * 8192 + tid * 8 + g * 2048]);
                    gload_lds16(b + g * rowskip, &sB[(buf ^ 1) * 8192 + tid * 8 + g * 2048]);
                }
            }
            #pragma unroll
            for (int h = 0; h < 2; h++) {
                bf16x8 av[4], bv[4];
                #pragma unroll
                for (int m = 0; m < 4; m++) {
                    av[m] = *(const bf16x8*)&sA[buf * 8192 + offA[h][m]];
                    bv[m] = *(const bf16x8*)&sB[buf * 8192 + offB[h][m]];
                }
                #pragma unroll
                for (int m = 0; m < 4; m++)
                    #pragma unroll
                    for (int n = 0; n < 4; n++)
                        acc[m][n] = MFMA16(av[m], bv[n], acc[m][n]);
            }
        }
        float* Cz = CP0 + (size_t)z * CP0_SL;
        #pragma unroll
        for (int m = 0; m < 4; m++)
            #pragma unroll
            for (int rr = 0; rr < 4; rr++) {
                int gm = m0 + wrow + m * 16 + cb * 4 + rr;
                #pragma unroll
                for (int n = 0; n < 4; n++) {
                    int cg = n0 + wcol + n * 16 + fm;
                    Cz[(size_t)gm * 1024 + cg] = acc[m][n][rr];
                }
            }
    } else if (bx < 768) {                  // WT1/WT2 LDS transposes
        int b2 = bx - 256;
        if (b2 < 256) wtrans4(c1w, WT1, b2 * 4, tid, smem);
        else          wtrans4(c2w, WT2, (b2 - 256) * 4, tid, smem);
    } else {                                // words / conv1d_w / fc_w casts
        int b2 = bx - 768;
        if (b2 < 640)       cast8(words, Wordsb, b2 * 256 + tid);
        else if (b2 < 1152) cast8(c1dw, C1b, (b2 - 640) * 256 + tid);
        else                cast8(fcw, Fb, (b2 - 1152) * 256 + tid);
    }
}

// ============== K3: conv0 epilogue (4 slices, relu) || word gram ==============
__global__ __launch_bounds__(256) void d3_kernel(
    const float* __restrict__ CP0, const float* __restrict__ c0b,
    bf16_t* __restrict__ Astack, const bf16_t* __restrict__ Wordsb,
    float* __restrict__ GR)
{
    __shared__ __align__(16) bf16_t smem[20480];   // 40KB (gram path only)
    int bx = blockIdx.x, tid = threadIdx.x;
    if (bx < 512) {
        int idx8 = bx * 256 + tid;          // < 131072 ; 8 elems each
        size_t base = (size_t)idx8 * 8;
        int nb = (int)(base & 1023);
        f32x4 s0 = *(const f32x4*)(c0b + nb);
        f32x4 s1 = *(const f32x4*)(c0b + nb + 4);
        #pragma unroll
        for (int z = 0; z < 4; z++) {
            const float* p = CP0 + (size_t)z * CP0_SL + base;
            s0 += *(const f32x4*)p;
            s1 += *(const f32x4*)(p + 4);
        }
        bf16x8 o;
        #pragma unroll
        for (int e = 0; e < 4; e++) {
            o[e]     = (bf16_t)fmaxf(s0[e], 0.f);
            o[4 + e] = (bf16_t)fmaxf(s1[e], 0.f);
        }
        *(bf16x8*)(Astack + base) = o;
    } else {
        // gram: one block per i; stage 20 word rows (40KB) then 400 dots
        int i = bx - 512;
        const bf16_t* Wr = Wordsb + (size_t)i * 20480;
        #pragma unroll
        for (int c = 0; c < 10; c++)
            gload_lds16(Wr + (c * 256 + tid) * 8, smem + (c * 256 + tid) * 8);
        __syncthreads();
        int wave = tid >> 6, lane = tid & 63;
        for (int r = 0; r < 100; ++r) {
            int p = wave * 100 + r;
            int w1 = p / 20, w2 = p % 20;
            const bf16_t* a = smem + w1 * 1024 + lane * 16;
            const bf16_t* b = smem + w2 * 1024 + lane * 16;
            bf16x8 a0 = *(const bf16x8*)a, a1 = *(const bf16x8*)(a + 8);
            bf16x8 b0 = *(const bf16x8*)b, b1 = *(const bf16x8*)(b + 8);
            float s = 0.f;
            #pragma unroll
            for (int e = 0; e < 8; e++)
                s += (float)a0[e] * (float)b0[e] + (float)a1[e] * (float)b1[e];
            #pragma unroll
            for (int o = 32; o; o >>= 1) s += __shfl_xor(s, o, 64);
            if (lane == 0) GR[(size_t)i * 400 + p] = s;
        }
    }
}

// == K4: conv1 splitK1 (bias+relu -> A2b) || c1d0 -> VCb rows 0..1023 ==========
__global__ __launch_bounds__(256) void d4_kernel(
    const bf16_t* __restrict__ Astack, const bf16_t* __restrict__ WT1,
    const float* __restrict__ c1b, bf16_t* __restrict__ A2b,
    const bf16_t* __restrict__ C1b, const float* __restrict__ c1db,
    bf16_t* __restrict__ VCb)
{
    __shared__ __align__(16) bf16_t smem[16384];
    bf16_t* sA = smem; bf16_t* sB = smem + 8192;
    int bx = blockIdx.x;
    if (bx < 64) {           // conv1: M=256 N=1024 K=4096, splitK1, relu
        int xt = bx & 3, yt = bx >> 2;
        gemm64(Astack, WT1, 1024, 4096, xt * 64, yt * 64, 0, 64,
               xt * 64, yt * 64, sA, sB, nullptr, c1b, A2b, 1);
    } else {                 // c1d0: M=1024 N=1024 K=1024, splitK1 + bias
        int b2 = bx - 64;    // 0..255
        int xt = b2 & 15, yt = b2 >> 4;
        gemm64(Astack, C1b, 1024, 1024, xt * 64, yt * 64, 0, 16,
               xt * 64, yt * 64, sA, sB, nullptr, c1db, VCb, 0);
    }
}

// == K5: conv2 splitK1 (bias+relu -> A3b) || c1d1 || attn cols<1024 || rn0 =====
__global__ __launch_bounds__(256) void d6_kernel(
    const bf16_t* __restrict__ A2b, const bf16_t* __restrict__ WT2,
    const float* __restrict__ c2b, bf16_t* __restrict__ A3b,
    const bf16_t* __restrict__ C1b, const float* __restrict__ c1db,
    const bf16_t* __restrict__ Wordsb, bf16_t* __restrict__ VCb,
    float* __restrict__ CPat, float* __restrict__ VN)
{
    __shared__ __align__(16) bf16_t smem[16384];
    bf16_t* sA = smem; bf16_t* sB = smem + 8192;
    int bx = blockIdx.x, tid = threadIdx.x;
    if (bx < 16) {           // conv2: M=64 N=1024 K=4096, splitK1, relu
        gemm64(A2b, WT2, 1024, 4096, 0, bx * 64, 0, 64,
               0, bx * 64, sA, sB, nullptr, c2b, A3b, 1);
    } else if (bx < 336) {   // attn0: M=1280, cols 0..1023, K=1024
        int g = bx - 16;                    // 0..319
        int xt = g % 20, yt = g / 20;
        gemm64(Wordsb, VCb, 1344, 1024, xt * 64, yt * 64, 0, 16,
               xt * 64, yt * 64, sA, sB, CPat, nullptr, nullptr, 0);
    } else if (bx < 400) {   // c1d1: M=256 N=1024 K=1024 -> VCb rows 1024..1279
        int g = bx - 336;
        int xt = g & 3, yt = g >> 2;
        gemm64(A2b, C1b, 1024, 1024, xt * 64, yt * 64, 0, 16,
               1024 + xt * 64, yt * 64, sA, sB, nullptr, c1db, VCb, 0);
    } else {                 // rownorm rows 0..1023
        int r = (bx - 400) * 4 + (tid >> 6);
        rownorm_row(VCb, VN, r, tid);
    }
}

// == K6: c1d2+fc from A3b || attn cols 1024..1279 || sim0 || rn-mid ============
__global__ __launch_bounds__(256) void d7_kernel(
    const bf16_t* __restrict__ A3b, const bf16_t* __restrict__ C1b,
    const bf16_t* __restrict__ Fb,
    const float* __restrict__ c1db, const float* __restrict__ fcb,
    bf16_t* __restrict__ VCb, float* __restrict__ GV,
    const bf16_t* __restrict__ Wordsb, float* __restrict__ CPat,
    const float* __restrict__ GR, float* __restrict__ VN,
    const int* __restrict__ wmask, float* __restrict__ SA)
{
    __shared__ __align__(16) bf16_t smem[16384];   // 32KB
    bf16_t* sA = smem; bf16_t* sB = smem + 8192;
    const int bx = blockIdx.x, tid = threadIdx.x;
    if (bx < 16) {           // c1d2: M=64 N=1024 K=1024 -> VCb rows 1280..1343
        gemm64(A3b, C1b, 1024, 1024, 0, bx * 64, 0, 16,
               1280, bx * 64, sA, sB, nullptr, c1db, VCb, 0);
    } else if (bx < 32) {    // fc: M=64 N=1024 K=1024 -> GV (f32 + bias)
        int yt = bx - 16;
        gemm64(A3b, Fb, 1024, 1024, 0, yt * 64, 0, 16,
               0, yt * 64, sA, sB, GV, fcb, nullptr, 0);
    } else if (bx < 112) {   // attn1: cols 1024..1279
        int g = bx - 32;                    // 0..79
        int xt = g % 20, yt = g / 20;
        gemm64(Wordsb, VCb, 1344, 1024, xt * 64, 1024 + yt * 64, 0, 16,
               xt * 64, 1024 + yt * 64, sA, sB, CPat, nullptr, nullptr, 0);
    } else if (bx < 368) {   // sim for stacked cols 0..1023
        int s = bx - 112;                   // 0..255
        int i = s >> 2, seg = s & 3;
        float* Gs  = (float*)smem;
        float* msk = Gs + 400;
        for (int q = tid; q < 400; q += 256) Gs[q] = GR[(size_t)i * 400 + q];
        if (tid < 20) msk[tid] = (wmask[i * 20 + tid] != 0) ? 1.f : 0.f;
        __syncthreads();
        sim_compute(i, seg * 256 + tid, CPat, VN, Gs, msk, SA);
    } else {                 // rownorm rows 1024..1279
        int r = 1024 + (bx - 368) * 4 + (tid >> 6);
        rownorm_row(VCb, VN, r, tid);
    }
}

// = K7: attn cols 1280.. || rownorm 1280.. || gscore || sim cols 1024..1279 ====
__global__ __launch_bounds__(256) void d8_kernel(
    const bf16_t* __restrict__ Wordsb, const bf16_t* __restrict__ VCb,
    float* __restrict__ CPat, float* __restrict__ VN,
    const float* __restrict__ sent, const float* __restrict__ GV,
    float* __restrict__ GS, const float* __restrict__ GR,
    const int* __restrict__ wmask, float* __restrict__ SA)
{
    __shared__ __align__(16) bf16_t smem[16384];
    bf16_t* sA = smem; bf16_t* sB = smem + 8192;
    int bx = blockIdx.x, tid = threadIdx.x;
    if (bx < 20) {           // attn2
        gemm64(Wordsb, VCb, 1344, 1024, bx * 64, 1280, 0, 16,
               bx * 64, 1280, sA, sB, CPat, nullptr, nullptr, 0);
    } else if (bx < 36) {    // rownorm rows 1280..1343
        int r = 1280 + (bx - 20) * 4 + (tid >> 6);
        rownorm_row(VCb, VN, r, tid);
    } else if (bx < 1060) {  // gscore (cosine of sentences vs GV)
        int item = (bx - 36) * 4 + (tid >> 6);
        int i = item >> 6, j = item & 63;
        int lane = tid & 63;
        const float* a = sent + (size_t)i * 1024;
        const float* b = GV + (size_t)j * 1024;
        float sab = 0.f, saa = 0.f, sbb = 0.f;
        #pragma unroll
        for (int q = 0; q < 16; q++) {
            int d = lane + 64 * q;
            float av = a[d], bv = b[d];
            sab += av * bv; saa += av * av; sbb += bv * bv;
        }
        #pragma unroll
        for (int o = 32; o; o >>= 1) {
            sab += __shfl_xor(sab, o, 64);
            saa += __shfl_xor(saa, o, 64);
            sbb += __shfl_xor(sbb, o, 64);
        }
        if (lane == 0)
            GS[item] = sab / (fmaxf(sqrtf(saa), 1e-8f) * fmaxf(sqrtf(sbb), 1e-8f));
    } else {                 // sim cols 1024..1279
        int i = bx - 1060;
        float* Gs  = (float*)smem;
        float* msk = Gs + 400;
        for (int q = tid; q < 400; q += 256) Gs[q] = GR[(size_t)i * 400 + q];
        if (tid < 20) msk[tid] = (wmask[i * 20 + tid] != 0) ? 1.f : 0.f;
        __syncthreads();
        sim_compute(i, 1024 + tid, CPat, VN, Gs, msk, SA);
    }
}

// ================= K8: sim cols 1280..1343 ====================================
__global__ __launch_bounds__(256) void d9_kernel(
    const float* __restrict__ CPat, const float* __restrict__ GR,
    const float* __restrict__ VN, const int* __restrict__ wmask,
    float* __restrict__ SA)
{
    __shared__ float Gs[400];
    __shared__ float msk[20];
    int i = blockIdx.x, tid = threadIdx.x;
    for (int q = tid; q < 400; q += 256) Gs[q] = GR[(size_t)i * 400 + q];
    if (tid < 20) msk[tid] = (wmask[i * 20 + tid] != 0) ? 1.f : 0.f;
    __syncthreads();
    if (tid < 64) sim_compute(i, 1280 + tid, CPat, VN, Gs, msk, SA);
}

// ================= K9: scores + positive_map ==================================
__global__ __launch_bounds__(256) void d10_kernel(
    const float* __restrict__ SA, float* __restrict__ SC, float* __restrict__ out)
{
    int idx = blockIdx.x * 256 + threadIdx.x;   // 4096
    int i = idx >> 6, j = idx & 63;
    const float* row = SA + (size_t)idx * 21;
    float s = 0.f;
    #pragma unroll
    for (int t = 0; t < 21; t++) s += row[t];
    SC[idx] = s * (1.0f / 21.0f);
    if (i == j) {
        #pragma unroll
        for (int t = 0; t < 21; t++) out[1 + i * 21 + t] = row[t];
    }
}

// ================= K10: margin ranking loss ===================================
__global__ __launch_bounds__(256) void loss_kernel(
    const float* __restrict__ SC_, const float* __restrict__ GS_,
    float* __restrict__ out)
{
    __shared__ float d1[64], d2[64], red[4];
    int tid = threadIdx.x;
    if (tid < 64) { d1[tid] = SC_[tid * 65]; d2[tid] = GS_[tid * 65]; }
    __syncthreads();
    float acc = 0.f;
    for (int idx = tid; idx < 4096; idx += 256) {
        int i = idx >> 6, j = idx & 63;
        if (i != j) {
            float s = SC_[idx];
            acc += fmaxf(0.2f + s - d1[i], 0.f) + fmaxf(0.2f + s - d1[j], 0.f);
            float g = GS_[idx];
            acc += fmaxf(0.2f + g - d2[i], 0.f) + fmaxf(0.2f + g - d2[j], 0.f);
        }
    }
    #pragma unroll
    for (int o = 32; o; o >>= 1) acc += __shfl_xor(acc, o, 64);
    if ((tid & 63) == 0) red[tid >> 6] = acc;
    __syncthreads();
    if (tid == 0) out[0] = (red[0] + red[1] + red[2] + red[3]) * (1.0f / 64.0f);
}

// ------------------------------------------------------------------------------
extern "C" void kernel_launch(void* const* d_in, const int* in_sizes, int n_in,
                              void* d_out, int out_size, void* d_ws, size_t ws_size,
                              hipStream_t stream)
{
    const float* video     = (const float*)d_in[0];
    const float* words     = (const float*)d_in[1];
    const int*   w_masks   = (const int*)  d_in[2];
    const float* sentences = (const float*)d_in[3];
    const float* conv0_w   = (const float*)d_in[4];
    const float* conv0_b   = (const float*)d_in[5];
    const float* conv1_w   = (const float*)d_in[6];
    const float* conv1_b   = (const float*)d_in[7];
    const float* conv2_w   = (const float*)d_in[8];
    const float* conv2_b   = (const float*)d_in[9];
    const float* conv1d_w  = (const float*)d_in[10];
    const float* conv1d_b  = (const float*)d_in[11];
    const float* fc_w      = (const float*)d_in[12];
    const float* fc_b      = (const float*)d_in[13];
    float* out = (float*)d_out;
    float* ws = (float*)d_ws;

    // ---- flat workspace (float units) ----------------------------------------
    bf16_t* WT0    = (bf16_t*)(ws + 0);            // 1024x4096 bf16
    bf16_t* WT1    = (bf16_t*)(ws + 2097152);
    bf16_t* WT2    = (bf16_t*)(ws + 4194304);
    bf16_t* Vb     = (bf16_t*)(ws + 6291456);      // 4096x1024 bf16
    bf16_t* Wordsb = (bf16_t*)(ws + 8388608);      // 1,310,720 bf16
    bf16_t* C1b    = (bf16_t*)(ws + 9043968);      // 1,048,576 bf16
    bf16_t* Fb     = (bf16_t*)(ws + 9568256);      // 1,048,576 bf16
    bf16_t* Astack = (bf16_t*)(ws + 10092544);     // 1024x1024 bf16 (conv0 out)
    bf16_t* A2b    = (bf16_t*)(ws + 10616832);     // 256x1024 bf16 (conv1 out)
    bf16_t* A3b    = (bf16_t*)(ws + 10747904);     // 64x1024 bf16 (conv2 out)
    bf16_t* VCb    = (bf16_t*)(ws + 10780672);     // 1344x1024 bf16 (STACKED)
    float*  CP0    = ws + 11468800;                // 4 x 1,048,576 f
    float*  CPat   = ws + 15663104;                // 1,720,320 f (single slice)
    float*  VN     = ws + 17383424;                // 1,344
    float*  GR     = ws + 17384768;                // 25,600
    float*  SA     = ws + 17410368;                // 86,016
    float*  SC     = ws + 17496384;                // 4,096
    float*  GV     = ws + 17500480;                // 65,536
    float*  GS     = ws + 17566016;                // 4,096 (ends 17,570,112)

    dim3 blk(256);

    // K1: WT0 transpose + video cast
    prep0_kernel<<<2304, blk, 0, stream>>>(conv0_w, WT0, video, Vb);
    // K2: conv0 GEMM || WT1/WT2 transposes || casts
    d2_kernel<<<2432, blk, 0, stream>>>(Vb, WT0, CP0, conv1_w, conv2_w, WT1, WT2,
                                        words, Wordsb, conv1d_w, C1b, fc_w, Fb);
    // K3: conv0 epi || gram
    d3_kernel<<<576, blk, 0, stream>>>(CP0, conv0_b, Astack, Wordsb, GR);
    // K4: conv1 (splitK1, fused) || c1d0 -> VCb[0..1024)
    d4_kernel<<<320, blk, 0, stream>>>(Astack, WT1, conv1_b, A2b, C1b, conv1d_b, VCb);
    // K5: conv2 (splitK1, fused) || attn0 || c1d1 -> VCb[1024..1280) || rownorm0
    d6_kernel<<<656, blk, 0, stream>>>(A2b, WT2, conv2_b, A3b, C1b, conv1d_b,
                                       Wordsb, VCb, CPat, VN);
    // K6: c1d2+fc from A3b || attn1 || sim0 || rownorm-mid
    d7_kernel<<<432, blk, 0, stream>>>(A3b, C1b, Fb, conv1d_b, fc_b,
                                       VCb, GV, Wordsb, CPat, GR, VN, w_masks, SA);
    // K7: attn2 || rownorm-hi || gscore || sim-mid
    d8_kernel<<<1124, blk, 0, stream>>>(Wordsb, VCb, CPat, VN, sentences, GV, GS,
                                        GR, w_masks, SA);
    // K8-K10: sim tail, scores+posmap, loss
    d9_kernel<<<64, blk, 0, stream>>>(CPat, GR, VN, w_masks, SA);
    d10_kernel<<<16, blk, 0, stream>>>(SA, SC, out);
    loss_kernel<<<1, blk, 0, stream>>>(SC, GS, out);
}

// Round 5
// 274.860 us; speedup vs baseline: 1.2002x; 1.0605x over previous
//
#include <hip/hip_runtime.h>
#include <cmath>
#include <cstdint>

// B=64, T=64, W=20, D=1024, K=4, STRIDE=4 ; conv lengths 64->16->4->1 ; T_total=21
// VCb is STACKED: rows [0,1024)=conv0-level (j=r>>4,t=r&15), [1024,1280)=conv1-level
// (j=(r-1024)>>2, t=16+((r-1024)&3)), [1280,1344)=conv2-level (j=r-1280, t=20).

typedef __bf16 bf16_t;
typedef bf16_t bf16x8 __attribute__((ext_vector_type(8)));
typedef bf16_t bf16x4 __attribute__((ext_vector_type(4)));
typedef bf16_t bf16x2 __attribute__((ext_vector_type(2)));
typedef float  f32x4  __attribute__((ext_vector_type(4)));

#define CP0_SL   1048576

#define MFMA16(a,b,c) __builtin_amdgcn_mfma_f32_16x16x32_bf16(a, b, c, 0, 0, 0)

__device__ __forceinline__ void gload_lds16(const void* g, void* l) {
    __builtin_amdgcn_global_load_lds(
        (const __attribute__((address_space(1))) void*)g,
        (__attribute__((address_space(3))) void*)l, 16, 0, 0);
}

// swizzled LDS offset (bf16 units): physical chunk = c ^ (row&7). row stride 64 bf16.
__device__ __forceinline__ int swz(int r, int c) { return (r * 8 + (c ^ (r & 7))) * 8; }

// ---------------- LDS-staged (i,k)->(k,i) weight transpose, 4 o-rows/block ----
// wt[o][k*1024+i] = w[o][i*4+k].  Coalesced reads AND writes.
__device__ __forceinline__ void wtrans4(const float* __restrict__ w,
                                        bf16_t* __restrict__ wt,
                                        int o0, int tid, bf16_t* lds /*16384*/)
{
    #pragma unroll
    for (int oo = 0; oo < 4; oo++) {
        const float* src = w + ((size_t)(o0 + oo) << 12);
        #pragma unroll
        for (int q = 0; q < 2; q++) {
            f32x4 va = *(const f32x4*)(src + tid * 16 + q * 8);      // i = tid*4+2q
            f32x4 vb = *(const f32x4*)(src + tid * 16 + q * 8 + 4);  // i = tid*4+2q+1
            int ib = tid * 4 + 2 * q;
            #pragma unroll
            for (int k = 0; k < 4; k++) {
                bf16x2 p2 = { (bf16_t)va[k], (bf16_t)vb[k] };
                *(bf16x2*)(lds + oo * 4096 + k * 1024 + ib) = p2;
            }
        }
    }
    __syncthreads();
    #pragma unroll
    for (int oo = 0; oo < 4; oo++) {
        bf16x8 v0 = *(bf16x8*)(lds + oo * 4096 + tid * 16);
        bf16x8 v1 = *(bf16x8*)(lds + oo * 4096 + tid * 16 + 8);
        bf16_t* dst = wt + ((size_t)(o0 + oo) << 12) + tid * 16;
        *(bf16x8*)dst       = v0;
        *(bf16x8*)(dst + 8) = v1;
    }
}

// ---------------- wide f32 -> bf16 cast, 8 elems/thread -----------------------
__device__ __forceinline__ void cast8(const float* __restrict__ s,
                                      bf16_t* __restrict__ d, int idx8)
{
    f32x4 a = *(const f32x4*)(s + (size_t)idx8 * 8);
    f32x4 b = *(const f32x4*)(s + (size_t)idx8 * 8 + 4);
    bf16x8 o;
    #pragma unroll
    for (int e = 0; e < 4; e++) { o[e] = (bf16_t)a[e]; o[4 + e] = (bf16_t)b[e]; }
    *(bf16x8*)(d + (size_t)idx8 * 8) = o;
}

// ---------------- shared 64x64 bf16 MFMA NT tile (double-buffered) ------------
// Output: v = acc (+bias[cg] if bias) (relu if relu); Dbf ? bf16 : f32.
__device__ __forceinline__ void gemm64(
    const bf16_t* __restrict__ A, const bf16_t* __restrict__ B,
    int Nc, int K, int m0A, int n0B, int k0, int nIt, int m0C, int n0C,
    bf16_t* sA, bf16_t* sB,
    float* __restrict__ Cf, const float* __restrict__ bias, bf16_t* __restrict__ Dbf,
    int relu)
{
    const int tid  = threadIdx.x;
    const int lane = tid & 63, wave = tid >> 6;
    const int sr = tid >> 3, pc = tid & 7, lc = pc ^ (sr & 7);
    const bf16_t* Ag = A + (size_t)(m0A + sr) * K + k0 + lc * 8;
    const bf16_t* Bg = B + (size_t)(n0B + sr) * K + k0 + lc * 8;
    const size_t rowskip = (size_t)32 * K;
    const int wr = (wave >> 1) * 32, wc = (wave & 1) * 32;
    const int fm = lane & 15, cb = lane >> 4;
    int offA[2][2], offB[2][2];
    #pragma unroll
    for (int h = 0; h < 2; h++) {
        offA[h][0] = swz(wr +      fm, cb + h * 4);
        offA[h][1] = swz(wr + 16 + fm, cb + h * 4);
        offB[h][0] = swz(wc +      fm, cb + h * 4);
        offB[h][1] = swz(wc + 16 + fm, cb + h * 4);
    }
    f32x4 acc[2][2];
    #pragma unroll
    for (int a = 0; a < 2; a++)
        #pragma unroll
        for (int b = 0; b < 2; b++) acc[a][b] = (f32x4){0.f, 0.f, 0.f, 0.f};

    gload_lds16(Ag,           sA + tid * 8);
    gload_lds16(Ag + rowskip, sA + 2048 + tid * 8);
    gload_lds16(Bg,           sB + tid * 8);
    gload_lds16(Bg + rowskip, sB + 2048 + tid * 8);
    for (int it = 0; it < nIt; ++it) {
        const int buf = it & 1;
        const bf16_t* cA = sA + buf * 4096;
        const bf16_t* cB = sB + buf * 4096;
        __syncthreads();
        if (it + 1 < nIt) {
            const bf16_t* a = Ag + (it + 1) * 64;
            const bf16_t* b = Bg + (it + 1) * 64;
            bf16_t* dA = sA + (buf ^ 1) * 4096;
            bf16_t* dB = sB + (buf ^ 1) * 4096;
            gload_lds16(a,           dA + tid * 8);
            gload_lds16(a + rowskip, dA + 2048 + tid * 8);
            gload_lds16(b,           dB + tid * 8);
            gload_lds16(b + rowskip, dB + 2048 + tid * 8);
        }
        #pragma unroll
        for (int h = 0; h < 2; h++) {
            bf16x8 a0 = *(const bf16x8*)&cA[offA[h][0]];
            bf16x8 a1 = *(const bf16x8*)&cA[offA[h][1]];
            bf16x8 b0 = *(const bf16x8*)&cB[offB[h][0]];
            bf16x8 b1 = *(const bf16x8*)&cB[offB[h][1]];
            acc[0][0] = MFMA16(a0, b0, acc[0][0]);
            acc[0][1] = MFMA16(a0, b1, acc[0][1]);
            acc[1][0] = MFMA16(a1, b0, acc[1][0]);
            acc[1][1] = MFMA16(a1, b1, acc[1][1]);
        }
    }
    // C/D layout: col = lane&15, row = (lane>>4)*4 + reg   [verified m89/m91]
    #pragma unroll
    for (int im = 0; im < 2; im++)
        #pragma unroll
        for (int rr = 0; rr < 4; rr++) {
            int gm = m0C + wr + im * 16 + cb * 4 + rr;
            #pragma unroll
            for (int in_ = 0; in_ < 2; in_++) {
                int cg = n0C + wc + in_ * 16 + fm;
                float v = acc[im][in_][rr];
                if (bias) v += bias[cg];
                if (relu) v = fmaxf(v, 0.f);
                if (Dbf) Dbf[(size_t)gm * Nc + cg] = (bf16_t)v;
                else     Cf[(size_t)gm * Nc + cg] = v;
            }
        }
}

// ---------------- wave-per-row L2 norm of a VCb row ---------------------------
__device__ __forceinline__ void rownorm_row(const bf16_t* __restrict__ VCb,
                                            float* __restrict__ VN, int r, int tid)
{
    const int lane = tid & 63;
    const bf16_t* x = VCb + ((size_t)r << 10) + lane * 16;
    bf16x8 v0 = *(const bf16x8*)x, v1 = *(const bf16x8*)(x + 8);
    float s = 0.f;
    #pragma unroll
    for (int e = 0; e < 8; e++) {
        float a = (float)v0[e], b = (float)v1[e];
        s += a * a + b * b;
    }
    #pragma unroll
    for (int o = 32; o; o >>= 1) s += __shfl_xor(s, o, 64);
    if (lane == 0) VN[r] = sqrtf(s);
}

// ---------------- per-(i, stacked-col) sim (single CPat slice) ----------------
__device__ __forceinline__ void sim_compute(
    int i, int c, const float* __restrict__ CPat, const float* __restrict__ VN,
    const float* Gs, const float* msk, float* __restrict__ SA)
{
    float s[20], p[20];
    float mx = -1e30f;
    #pragma unroll
    for (int w = 0; w < 20; w++) {
        s[w] = CPat[(size_t)(i * 20 + w) * 1344 + c];
        if (msk[w] != 0.f) mx = fmaxf(mx, s[w]);
    }
    float denom = 0.f, num = 0.f;
    #pragma unroll
    for (int w = 0; w < 20; w++) {
        p[w] = (msk[w] != 0.f) ? __expf(s[w] - mx) : 0.f;
        denom += p[w];
        num   += p[w] * s[w];
    }
    float quad = 0.f;
    #pragma unroll
    for (int w = 0; w < 20; w++) {
        float cc = 0.f;
        #pragma unroll
        for (int w2 = 0; w2 < 20; w2++) cc += Gs[w * 20 + w2] * p[w2];
        quad += p[w] * cc;
    }
    float dot = num / denom;
    float vsn = sqrtf(fmaxf(quad, 0.f)) / denom;
    float sim = dot / (fmaxf(VN[c], 1e-8f) * fmaxf(vsn, 1e-8f));
    int j, t;
    if (c < 1024)      { j = c >> 4;          t = c & 15; }
    else if (c < 1280) { j = (c - 1024) >> 2; t = 16 + ((c - 1024) & 3); }
    else               { j = c - 1280;        t = 20; }
    SA[((size_t)i * 64 + j) * 21 + t] = sim;
}

// ================= K1: WT0 LDS-transpose + video cast =========================
__global__ __launch_bounds__(256) void prep0_kernel(
    const float* __restrict__ c0w, bf16_t* __restrict__ WT0,
    const float* __restrict__ video, bf16_t* __restrict__ Vb)
{
    __shared__ __align__(16) bf16_t lds[16384];
    int bx = blockIdx.x;
    if (bx < 256) wtrans4(c0w, WT0, bx * 4, threadIdx.x, lds);
    else          cast8(video, Vb, (bx - 256) * 256 + threadIdx.x);
}

// ===== K2: conv0 128x128 GEMM (splitK x4) || WT1/WT2 transposes || casts ======
__global__ __launch_bounds__(256) void d2_kernel(
    const bf16_t* __restrict__ Vb, const bf16_t* __restrict__ WT0, float* __restrict__ CP0,
    const float* __restrict__ c1w, const float* __restrict__ c2w,
    bf16_t* __restrict__ WT1, bf16_t* __restrict__ WT2,
    const float* __restrict__ words, bf16_t* __restrict__ Wordsb,
    const float* __restrict__ c1dw, bf16_t* __restrict__ C1b,
    const float* __restrict__ fcw, bf16_t* __restrict__ Fb)
{
    __shared__ __align__(16) bf16_t smem[32768];   // 64KB
    const int bx = blockIdx.x, tid = threadIdx.x;
    if (bx < 256) {
        // 128x128 tile, 4 waves of 64x64, BK=64, dbuf; splitK x4 (Kchunk 1024)
        bf16_t* sA = smem;            // 2 x 8192
        bf16_t* sB = smem + 16384;    // 2 x 8192
        const int z = bx >> 6, rem = bx & 63, xt = rem & 7, yt = rem >> 3;
        const int m0 = xt * 128, n0 = yt * 128, k0 = z * 1024;
        const int lane = tid & 63, wave = tid >> 6;
        const int sr = tid >> 3, pc = tid & 7, lc = pc ^ (sr & 7);
        const bf16_t* Ag = Vb  + (size_t)(m0 + sr) * 4096 + k0 + lc * 8;
        const bf16_t* Bg = WT0 + (size_t)(n0 + sr) * 4096 + k0 + lc * 8;
        const size_t rowskip = (size_t)32 * 4096;
        const int wrow = (wave >> 1) * 64, wcol = (wave & 1) * 64;
        const int fm = lane & 15, cb = lane >> 4;
        int offA[2][4], offB[2][4];
        #pragma unroll
        for (int h = 0; h < 2; h++)
            #pragma unroll
            for (int m = 0; m < 4; m++) {
                offA[h][m] = swz(wrow + m * 16 + fm, cb + h * 4);
                offB[h][m] = swz(wcol + m * 16 + fm, cb + h * 4);
            }
        f32x4 acc[4][4];
        #pragma unroll
        for (int m = 0; m < 4; m++)
            #pragma unroll
            for (int n = 0; n < 4; n++) acc[m][n] = (f32x4){0.f, 0.f, 0.f, 0.f};

        #pragma unroll
        for (int g = 0; g < 4; g++) {
            gload_lds16(Ag + g * rowskip, &sA[tid * 8 + g * 2048]);
            gload_lds16(Bg + g * rowskip, &sB[tid * 8 + g * 2048]);
        }
        for (int it = 0; it < 16; ++it) {
            const int buf = it & 1;
            __syncthreads();
            if (it < 15) {
                const bf16_t* a = Ag + (it + 1) * 64;
                const bf16_t* b = Bg + (it + 1) * 64;
                #pragma unroll
                for (int g = 0; g < 4; g++) {
                    gload_lds16(a + g * rowskip, &sA[(buf ^ 1) * 8192 + tid * 8 + g * 2048]);
                    gload_lds16(b + g * rowskip, &sB[(buf ^ 1) * 8192 + tid * 8 + g * 2048]);
                }
            }
            #pragma unroll
            for (int h = 0; h < 2; h++) {
                bf16x8 av[4], bv[4];
                #pragma unroll
                for (int m = 0; m < 4; m++) {
                    av[m] = *(const bf16x8*)&sA[buf * 8192 + offA[h][m]];
                    bv[m] = *(const bf16x8*)&sB[buf * 8192 + offB[h][m]];
                }
                #pragma unroll
                for (int m = 0; m < 4; m++)
                    #pragma unroll
                    for (int n = 0; n < 4; n++)
                        acc[m][n] = MFMA16(av[m], bv[n], acc[m][n]);
            }
        }
        float* Cz = CP0 + (size_t)z * CP0_SL;
        #pragma unroll
        for (int m = 0; m < 4; m++)
            #pragma unroll
            for (int rr = 0; rr < 4; rr++) {
                int gm = m0 + wrow + m * 16 + cb * 4 + rr;
                #pragma unroll
                for (int n = 0; n < 4; n++) {
                    int cg = n0 + wcol + n * 16 + fm;
                    Cz[(size_t)gm * 1024 + cg] = acc[m][n][rr];
                }
            }
    } else if (bx < 768) {                  // WT1/WT2 LDS transposes
        int b2 = bx - 256;
        if (b2 < 256) wtrans4(c1w, WT1, b2 * 4, tid, smem);
        else          wtrans4(c2w, WT2, (b2 - 256) * 4, tid, smem);
    } else {                                // words / conv1d_w / fc_w casts
        int b2 = bx - 768;
        if (b2 < 640)       cast8(words, Wordsb, b2 * 256 + tid);
        else if (b2 < 1152) cast8(c1dw, C1b, (b2 - 640) * 256 + tid);
        else                cast8(fcw, Fb, (b2 - 1152) * 256 + tid);
    }
}

// ====== K3: conv0 epilogue (4 slices, relu) || word gram (wave-per-pair) ======
__global__ __launch_bounds__(256) void d3_kernel(
    const float* __restrict__ CP0, const float* __restrict__ c0b,
    bf16_t* __restrict__ Astack, const bf16_t* __restrict__ Wordsb,
    float* __restrict__ GR)
{
    int bx = blockIdx.x, tid = threadIdx.x;
    if (bx < 512) {
        int idx8 = bx * 256 + tid;          // < 131072 ; 8 elems each
        size_t base = (size_t)idx8 * 8;
        int nb = (int)(base & 1023);
        f32x4 s0 = *(const f32x4*)(c0b + nb);
        f32x4 s1 = *(const f32x4*)(c0b + nb + 4);
        #pragma unroll
        for (int z = 0; z < 4; z++) {
            const float* p = CP0 + (size_t)z * CP0_SL + base;
            s0 += *(const f32x4*)p;
            s1 += *(const f32x4*)(p + 4);
        }
        bf16x8 o;
        #pragma unroll
        for (int e = 0; e < 4; e++) {
            o[e]     = (bf16_t)fmaxf(s0[e], 0.f);
            o[4 + e] = (bf16_t)fmaxf(s1[e], 0.f);
        }
        *(bf16x8*)(Astack + base) = o;
    } else {
        // gram: one wave per (i, w, w2) pair; rows read from L2-resident Wordsb
        int g = bx - 512;                   // 0..6399
        int i = g / 100, piece = g % 100;
        int wave = tid >> 6, lane = tid & 63;
        int pair = piece * 4 + wave;        // 0..399 = w*20+w2
        int w = pair / 20, w2 = pair % 20;
        const bf16_t* a = Wordsb + (((size_t)i * 20 + w)  << 10) + lane * 16;
        const bf16_t* b = Wordsb + (((size_t)i * 20 + w2) << 10) + lane * 16;
        bf16x8 a0 = *(const bf16x8*)a, a1 = *(const bf16x8*)(a + 8);
        bf16x8 b0 = *(const bf16x8*)b, b1 = *(const bf16x8*)(b + 8);
        float s = 0.f;
        #pragma unroll
        for (int e = 0; e < 8; e++)
            s += (float)a0[e] * (float)b0[e] + (float)a1[e] * (float)b1[e];
        #pragma unroll
        for (int o = 32; o; o >>= 1) s += __shfl_xor(s, o, 64);
        if (lane == 0) GR[(size_t)i * 400 + pair] = s;
    }
}

// == K4: conv1 splitK1 (bias+relu -> A2b) || c1d0 -> VCb rows 0..1023 ==========
__global__ __launch_bounds__(256) void d4_kernel(
    const bf16_t* __restrict__ Astack, const bf16_t* __restrict__ WT1,
    const float* __restrict__ c1b, bf16_t* __restrict__ A2b,
    const bf16_t* __restrict__ C1b, const float* __restrict__ c1db,
    bf16_t* __restrict__ VCb)
{
    __shared__ __align__(16) bf16_t smem[16384];
    bf16_t* sA = smem; bf16_t* sB = smem + 8192;
    int bx = blockIdx.x;
    if (bx < 64) {           // conv1: M=256 N=1024 K=4096, splitK1, relu
        int xt = bx & 3, yt = bx >> 2;
        gemm64(Astack, WT1, 1024, 4096, xt * 64, yt * 64, 0, 64,
               xt * 64, yt * 64, sA, sB, nullptr, c1b, A2b, 1);
    } else {                 // c1d0: M=1024 N=1024 K=1024, splitK1 + bias
        int b2 = bx - 64;    // 0..255
        int xt = b2 & 15, yt = b2 >> 4;
        gemm64(Astack, C1b, 1024, 1024, xt * 64, yt * 64, 0, 16,
               xt * 64, yt * 64, sA, sB, nullptr, c1db, VCb, 0);
    }
}

// == K5: conv2 splitK1 (bias+relu -> A3b) || c1d1 || attn cols<1024 || rn0 =====
__global__ __launch_bounds__(256) void d6_kernel(
    const bf16_t* __restrict__ A2b, const bf16_t* __restrict__ WT2,
    const float* __restrict__ c2b, bf16_t* __restrict__ A3b,
    const bf16_t* __restrict__ C1b, const float* __restrict__ c1db,
    const bf16_t* __restrict__ Wordsb, bf16_t* __restrict__ VCb,
    float* __restrict__ CPat, float* __restrict__ VN)
{
    __shared__ __align__(16) bf16_t smem[16384];
    bf16_t* sA = smem; bf16_t* sB = smem + 8192;
    int bx = blockIdx.x, tid = threadIdx.x;
    if (bx < 16) {           // conv2: M=64 N=1024 K=4096, splitK1, relu
        gemm64(A2b, WT2, 1024, 4096, 0, bx * 64, 0, 64,
               0, bx * 64, sA, sB, nullptr, c2b, A3b, 1);
    } else if (bx < 336) {   // attn0: M=1280, cols 0..1023, K=1024
        int g = bx - 16;                    // 0..319
        int xt = g % 20, yt = g / 20;
        gemm64(Wordsb, VCb, 1344, 1024, xt * 64, yt * 64, 0, 16,
               xt * 64, yt * 64, sA, sB, CPat, nullptr, nullptr, 0);
    } else if (bx < 400) {   // c1d1: M=256 N=1024 K=1024 -> VCb rows 1024..1279
        int g = bx - 336;
        int xt = g & 3, yt = g >> 2;
        gemm64(A2b, C1b, 1024, 1024, xt * 64, yt * 64, 0, 16,
               1024 + xt * 64, yt * 64, sA, sB, nullptr, c1db, VCb, 0);
    } else {                 // rownorm rows 0..1023
        int r = (bx - 400) * 4 + (tid >> 6);
        rownorm_row(VCb, VN, r, tid);
    }
}

// == K6: c1d2+fc from A3b || attn cols 1024..1279 || sim0 || rn-mid ============
__global__ __launch_bounds__(256) void d7_kernel(
    const bf16_t* __restrict__ A3b, const bf16_t* __restrict__ C1b,
    const bf16_t* __restrict__ Fb,
    const float* __restrict__ c1db, const float* __restrict__ fcb,
    bf16_t* __restrict__ VCb, float* __restrict__ GV,
    const bf16_t* __restrict__ Wordsb, float* __restrict__ CPat,
    const float* __restrict__ GR, float* __restrict__ VN,
    const int* __restrict__ wmask, float* __restrict__ SA)
{
    __shared__ __align__(16) bf16_t smem[16384];   // 32KB
    bf16_t* sA = smem; bf16_t* sB = smem + 8192;
    const int bx = blockIdx.x, tid = threadIdx.x;
    if (bx < 16) {           // c1d2: M=64 N=1024 K=1024 -> VCb rows 1280..1343
        gemm64(A3b, C1b, 1024, 1024, 0, bx * 64, 0, 16,
               1280, bx * 64, sA, sB, nullptr, c1db, VCb, 0);
    } else if (bx < 32) {    // fc: M=64 N=1024 K=1024 -> GV (f32 + bias)
        int yt = bx - 16;
        gemm64(A3b, Fb, 1024, 1024, 0, yt * 64, 0, 16,
               0, yt * 64, sA, sB, GV, fcb, nullptr, 0);
    } else if (bx < 112) {   // attn1: cols 1024..1279
        int g = bx - 32;                    // 0..79
        int xt = g % 20, yt = g / 20;
        gemm64(Wordsb, VCb, 1344, 1024, xt * 64, 1024 + yt * 64, 0, 16,
               xt * 64, 1024 + yt * 64, sA, sB, CPat, nullptr, nullptr, 0);
    } else if (bx < 368) {   // sim for stacked cols 0..1023
        int s = bx - 112;                   // 0..255
        int i = s >> 2, seg = s & 3;
        float* Gs  = (float*)smem;
        float* msk = Gs + 400;
        for (int q = tid; q < 400; q += 256) Gs[q] = GR[(size_t)i * 400 + q];
        if (tid < 20) msk[tid] = (wmask[i * 20 + tid] != 0) ? 1.f : 0.f;
        __syncthreads();
        sim_compute(i, seg * 256 + tid, CPat, VN, Gs, msk, SA);
    } else {                 // rownorm rows 1024..1279
        int r = 1024 + (bx - 368) * 4 + (tid >> 6);
        rownorm_row(VCb, VN, r, tid);
    }
}

// = K7: attn cols 1280.. || rownorm 1280.. || gscore || sim cols 1024..1279 ====
__global__ __launch_bounds__(256) void d8_kernel(
    const bf16_t* __restrict__ Wordsb, const bf16_t* __restrict__ VCb,
    float* __restrict__ CPat, float* __restrict__ VN,
    const float* __restrict__ sent, const float* __restrict__ GV,
    float* __restrict__ GS, const float* __restrict__ GR,
    const int* __restrict__ wmask, float* __restrict__ SA)
{
    __shared__ __align__(16) bf16_t smem[16384];
    bf16_t* sA = smem; bf16_t* sB = smem + 8192;
    int bx = blockIdx.x, tid = threadIdx.x;
    if (bx < 20) {           // attn2
        gemm64(Wordsb, VCb, 1344, 1024, bx * 64, 1280, 0, 16,
               bx * 64, 1280, sA, sB, CPat, nullptr, nullptr, 0);
    } else if (bx < 36) {    // rownorm rows 1280..1343
        int r = 1280 + (bx - 20) * 4 + (tid >> 6);
        rownorm_row(VCb, VN, r, tid);
    } else if (bx < 1060) {  // gscore (cosine of sentences vs GV)
        int item = (bx - 36) * 4 + (tid >> 6);
        int i = item >> 6, j = item & 63;
        int lane = tid & 63;
        const float* a = sent + (size_t)i * 1024;
        const float* b = GV + (size_t)j * 1024;
        float sab = 0.f, saa = 0.f, sbb = 0.f;
        #pragma unroll
        for (int q = 0; q < 16; q++) {
            int d = lane + 64 * q;
            float av = a[d], bv = b[d];
            sab += av * bv; saa += av * av; sbb += bv * bv;
        }
        #pragma unroll
        for (int o = 32; o; o >>= 1) {
            sab += __shfl_xor(sab, o, 64);
            saa += __shfl_xor(saa, o, 64);
            sbb += __shfl_xor(sbb, o, 64);
        }
        if (lane == 0)
            GS[item] = sab / (fmaxf(sqrtf(saa), 1e-8f) * fmaxf(sqrtf(sbb), 1e-8f));
    } else {                 // sim cols 1024..1279
        int i = bx - 1060;
        float* Gs  = (float*)smem;
        float* msk = Gs + 400;
        for (int q = tid; q < 400; q += 256) Gs[q] = GR[(size_t)i * 400 + q];
        if (tid < 20) msk[tid] = (wmask[i * 20 + tid] != 0) ? 1.f : 0.f;
        __syncthreads();
        sim_compute(i, 1024 + tid, CPat, VN, Gs, msk, SA);
    }
}

// ================= K8: sim cols 1280..1343 ====================================
__global__ __launch_bounds__(256) void d9_kernel(
    const float* __restrict__ CPat, const float* __restrict__ GR,
    const float* __restrict__ VN, const int* __restrict__ wmask,
    float* __restrict__ SA)
{
    __shared__ float Gs[400];
    __shared__ float msk[20];
    int i = blockIdx.x, tid = threadIdx.x;
    for (int q = tid; q < 400; q += 256) Gs[q] = GR[(size_t)i * 400 + q];
    if (tid < 20) msk[tid] = (wmask[i * 20 + tid] != 0) ? 1.f : 0.f;
    __syncthreads();
    if (tid < 64) sim_compute(i, 1280 + tid, CPat, VN, Gs, msk, SA);
}

// ================= K9: scores + positive_map ==================================
__global__ __launch_bounds__(256) void d10_kernel(
    const float* __restrict__ SA, float* __restrict__ SC, float* __restrict__ out)
{
    int idx = blockIdx.x * 256 + threadIdx.x;   // 4096
    int i = idx >> 6, j = idx & 63;
    const float* row = SA + (size_t)idx * 21;
    float s = 0.f;
    #pragma unroll
    for (int t = 0; t < 21; t++) s += row[t];
    SC[idx] = s * (1.0f / 21.0f);
    if (i == j) {
        #pragma unroll
        for (int t = 0; t < 21; t++) out[1 + i * 21 + t] = row[t];
    }
}

// ================= K10: margin ranking loss ===================================
__global__ __launch_bounds__(256) void loss_kernel(
    const float* __restrict__ SC_, const float* __restrict__ GS_,
    float* __restrict__ out)
{
    __shared__ float d1[64], d2[64], red[4];
    int tid = threadIdx.x;
    if (tid < 64) { d1[tid] = SC_[tid * 65]; d2[tid] = GS_[tid * 65]; }
    __syncthreads();
    float acc = 0.f;
    for (int idx = tid; idx < 4096; idx += 256) {
        int i = idx >> 6, j = idx & 63;
        if (i != j) {
            float s = SC_[idx];
            acc += fmaxf(0.2f + s - d1[i], 0.f) + fmaxf(0.2f + s - d1[j], 0.f);
            float g = GS_[idx];
            acc += fmaxf(0.2f + g - d2[i], 0.f) + fmaxf(0.2f + g - d2[j], 0.f);
        }
    }
    #pragma unroll
    for (int o = 32; o; o >>= 1) acc += __shfl_xor(acc, o, 64);
    if ((tid & 63) == 0) red[tid >> 6] = acc;
    __syncthreads();
    if (tid == 0) out[0] = (red[0] + red[1] + red[2] + red[3]) * (1.0f / 64.0f);
}

// ------------------------------------------------------------------------------
extern "C" void kernel_launch(void* const* d_in, const int* in_sizes, int n_in,
                              void* d_out, int out_size, void* d_ws, size_t ws_size,
                              hipStream_t stream)
{
    const float* video     = (const float*)d_in[0];
    const float* words     = (const float*)d_in[1];
    const int*   w_masks   = (const int*)  d_in[2];
    const float* sentences = (const float*)d_in[3];
    const float* conv0_w   = (const float*)d_in[4];
    const float* conv0_b   = (const float*)d_in[5];
    const float* conv1_w   = (const float*)d_in[6];
    const float* conv1_b   = (const float*)d_in[7];
    const float* conv2_w   = (const float*)d_in[8];
    const float* conv2_b   = (const float*)d_in[9];
    const float* conv1d_w  = (const float*)d_in[10];
    const float* conv1d_b  = (const float*)d_in[11];
    const float* fc_w      = (const float*)d_in[12];
    const float* fc_b      = (const float*)d_in[13];
    float* out = (float*)d_out;
    float* ws = (float*)d_ws;

    // ---- flat workspace (float units) ----------------------------------------
    bf16_t* WT0    = (bf16_t*)(ws + 0);            // 1024x4096 bf16
    bf16_t* WT1    = (bf16_t*)(ws + 2097152);
    bf16_t* WT2    = (bf16_t*)(ws + 4194304);
    bf16_t* Vb     = (bf16_t*)(ws + 6291456);      // 4096x1024 bf16
    bf16_t* Wordsb = (bf16_t*)(ws + 8388608);      // 1,310,720 bf16
    bf16_t* C1b    = (bf16_t*)(ws + 9043968);      // 1,048,576 bf16
    bf16_t* Fb     = (bf16_t*)(ws + 9568256);      // 1,048,576 bf16
    bf16_t* Astack = (bf16_t*)(ws + 10092544);     // 1024x1024 bf16 (conv0 out)
    bf16_t* A2b    = (bf16_t*)(ws + 10616832);     // 256x1024 bf16 (conv1 out)
    bf16_t* A3b    = (bf16_t*)(ws + 10747904);     // 64x1024 bf16 (conv2 out)
    bf16_t* VCb    = (bf16_t*)(ws + 10780672);     // 1344x1024 bf16 (STACKED)
    float*  CP0    = ws + 11468800;                // 4 x 1,048,576 f
    float*  CPat   = ws + 15663104;                // 1,720,320 f (single slice)
    float*  VN     = ws + 17383424;                // 1,344
    float*  GR     = ws + 17384768;                // 25,600
    float*  SA     = ws + 17410368;                // 86,016
    float*  SC     = ws + 17496384;                // 4,096
    float*  GV     = ws + 17500480;                // 65,536
    float*  GS     = ws + 17566016;                // 4,096 (ends 17,570,112)

    dim3 blk(256);

    // K1: WT0 transpose + video cast
    prep0_kernel<<<2304, blk, 0, stream>>>(conv0_w, WT0, video, Vb);
    // K2: conv0 GEMM || WT1/WT2 transposes || casts
    d2_kernel<<<2432, blk, 0, stream>>>(Vb, WT0, CP0, conv1_w, conv2_w, WT1, WT2,
                                        words, Wordsb, conv1d_w, C1b, fc_w, Fb);
    // K3: conv0 epi || gram (wave-per-pair, global reads)
    d3_kernel<<<6912, blk, 0, stream>>>(CP0, conv0_b, Astack, Wordsb, GR);
    // K4: conv1 (splitK1, fused) || c1d0 -> VCb[0..1024)
    d4_kernel<<<320, blk, 0, stream>>>(Astack, WT1, conv1_b, A2b, C1b, conv1d_b, VCb);
    // K5: conv2 (splitK1, fused) || attn0 || c1d1 -> VCb[1024..1280) || rownorm0
    d6_kernel<<<656, blk, 0, stream>>>(A2b, WT2, conv2_b, A3b, C1b, conv1d_b,
                                       Wordsb, VCb, CPat, VN);
    // K6: c1d2+fc from A3b || attn1 || sim0 || rownorm-mid
    d7_kernel<<<432, blk, 0, stream>>>(A3b, C1b, Fb, conv1d_b, fc_b,
                                       VCb, GV, Wordsb, CPat, GR, VN, w_masks, SA);
    // K7: attn2 || rownorm-hi || gscore || sim-mid
    d8_kernel<<<1124, blk, 0, stream>>>(Wordsb, VCb, CPat, VN, sentences, GV, GS,
                                        GR, w_masks, SA);
    // K8-K10: sim tail, scores+posmap, loss
    d9_kernel<<<64, blk, 0, stream>>>(CPat, GR, VN, w_masks, SA);
    d10_kernel<<<16, blk, 0, stream>>>(SA, SC, out);
    loss_kernel<<<1, blk, 0, stream>>>(SC, GS, out);
}

// Round 6
// 247.454 us; speedup vs baseline: 1.3331x; 1.1108x over previous
//
#include <hip/hip_runtime.h>
#include <cmath>
#include <cstdint>

// B=64, T=64, W=20, D=1024, K=4, STRIDE=4 ; conv lengths 64->16->4->1 ; T_total=21
// VCb is STACKED: rows [0,1024)=conv0-level (j=r>>4,t=r&15), [1024,1280)=conv1-level
// (j=(r-1024)>>2, t=16+((r-1024)&3)), [1280,1344)=conv2-level (j=r-1280, t=20).

typedef __bf16 bf16_t;
typedef bf16_t bf16x8 __attribute__((ext_vector_type(8)));
typedef bf16_t bf16x4 __attribute__((ext_vector_type(4)));
typedef bf16_t bf16x2 __attribute__((ext_vector_type(2)));
typedef float  f32x4  __attribute__((ext_vector_type(4)));

#define CP0_SL   1048576

#define MFMA16(a,b,c) __builtin_amdgcn_mfma_f32_16x16x32_bf16(a, b, c, 0, 0, 0)

__device__ __forceinline__ void gload_lds16(const void* g, void* l) {
    __builtin_amdgcn_global_load_lds(
        (const __attribute__((address_space(1))) void*)g,
        (__attribute__((address_space(3))) void*)l, 16, 0, 0);
}

// swizzle for BK=64 rows (8 chunks):   phys chunk = c ^ (r&7),  row stride 64 bf16
__device__ __forceinline__ int swz(int r, int c)    { return (r * 8  + (c ^ (r & 7)))  * 8; }
// swizzle for BK=128 rows (16 chunks): phys chunk = c ^ (r&15), row stride 128 bf16
__device__ __forceinline__ int swz128(int r, int c) { return (r * 16 + (c ^ (r & 15))) * 8; }

// ---------------- LDS-staged (i,k)->(k,i) weight transpose, 4 o-rows/block ----
__device__ __forceinline__ void wtrans4(const float* __restrict__ w,
                                        bf16_t* __restrict__ wt,
                                        int o0, int tid, bf16_t* lds /*16384*/)
{
    #pragma unroll
    for (int oo = 0; oo < 4; oo++) {
        const float* src = w + ((size_t)(o0 + oo) << 12);
        #pragma unroll
        for (int q = 0; q < 2; q++) {
            f32x4 va = *(const f32x4*)(src + tid * 16 + q * 8);
            f32x4 vb = *(const f32x4*)(src + tid * 16 + q * 8 + 4);
            int ib = tid * 4 + 2 * q;
            #pragma unroll
            for (int k = 0; k < 4; k++) {
                bf16x2 p2 = { (bf16_t)va[k], (bf16_t)vb[k] };
                *(bf16x2*)(lds + oo * 4096 + k * 1024 + ib) = p2;
            }
        }
    }
    __syncthreads();
    #pragma unroll
    for (int oo = 0; oo < 4; oo++) {
        bf16x8 v0 = *(bf16x8*)(lds + oo * 4096 + tid * 16);
        bf16x8 v1 = *(bf16x8*)(lds + oo * 4096 + tid * 16 + 8);
        bf16_t* dst = wt + ((size_t)(o0 + oo) << 12) + tid * 16;
        *(bf16x8*)dst       = v0;
        *(bf16x8*)(dst + 8) = v1;
    }
}

// ---------------- wide f32 -> bf16 cast, 8 elems/thread -----------------------
__device__ __forceinline__ void cast8(const float* __restrict__ s,
                                      bf16_t* __restrict__ d, int idx8)
{
    f32x4 a = *(const f32x4*)(s + (size_t)idx8 * 8);
    f32x4 b = *(const f32x4*)(s + (size_t)idx8 * 8 + 4);
    bf16x8 o;
    #pragma unroll
    for (int e = 0; e < 4; e++) { o[e] = (bf16_t)a[e]; o[4 + e] = (bf16_t)b[e]; }
    *(bf16x8*)(d + (size_t)idx8 * 8) = o;
}

// -------- 64x64 bf16 MFMA NT tile, BK=128, double-buffered (64KB LDS) ---------
// Output: v = acc (+bias[cg] if bias) (relu if relu); Dbf ? bf16 : f32.
__device__ __forceinline__ void gemm64(
    const bf16_t* __restrict__ A, const bf16_t* __restrict__ B,
    int Nc, int K, int m0A, int n0B, int k0, int nIt, int m0C, int n0C,
    bf16_t* sA, bf16_t* sB,            // each 2 x 8192 bf16
    float* __restrict__ Cf, const float* __restrict__ bias, bf16_t* __restrict__ Dbf,
    int relu)
{
    const int tid  = threadIdx.x;
    const int lane = tid & 63, wave = tid >> 6;
    // staging: 4 passes x 256 threads = 1024 chunks of 16B per matrix per buffer
    const bf16_t* AgP[4]; const bf16_t* BgP[4];
    #pragma unroll
    for (int g = 0; g < 4; g++) {
        int q = g * 256 + tid, row = q >> 4, pcc = q & 15, lcc = pcc ^ (row & 15);
        AgP[g] = A + (size_t)(m0A + row) * K + k0 + lcc * 8;
        BgP[g] = B + (size_t)(n0B + row) * K + k0 + lcc * 8;
    }
    const int wr = (wave >> 1) * 32, wc = (wave & 1) * 32;
    const int fm = lane & 15, cb = lane >> 4;
    int offA[4][2], offB[4][2];
    #pragma unroll
    for (int h = 0; h < 4; h++) {
        offA[h][0] = swz128(wr +      fm, cb + h * 4);
        offA[h][1] = swz128(wr + 16 + fm, cb + h * 4);
        offB[h][0] = swz128(wc +      fm, cb + h * 4);
        offB[h][1] = swz128(wc + 16 + fm, cb + h * 4);
    }
    f32x4 acc[2][2];
    #pragma unroll
    for (int a = 0; a < 2; a++)
        #pragma unroll
        for (int b = 0; b < 2; b++) acc[a][b] = (f32x4){0.f, 0.f, 0.f, 0.f};

    #pragma unroll
    for (int g = 0; g < 4; g++) {
        gload_lds16(AgP[g], sA + (g * 256 + tid) * 8);
        gload_lds16(BgP[g], sB + (g * 256 + tid) * 8);
    }
    for (int it = 0; it < nIt; ++it) {
        const int buf = it & 1;
        const bf16_t* cA = sA + buf * 8192;
        const bf16_t* cB = sB + buf * 8192;
        __syncthreads();
        if (it + 1 < nIt) {
            bf16_t* dA = sA + (buf ^ 1) * 8192;
            bf16_t* dB = sB + (buf ^ 1) * 8192;
            #pragma unroll
            for (int g = 0; g < 4; g++) {
                gload_lds16(AgP[g] + (it + 1) * 128, dA + (g * 256 + tid) * 8);
                gload_lds16(BgP[g] + (it + 1) * 128, dB + (g * 256 + tid) * 8);
            }
        }
        #pragma unroll
        for (int h = 0; h < 4; h++) {
            bf16x8 a0 = *(const bf16x8*)&cA[offA[h][0]];
            bf16x8 a1 = *(const bf16x8*)&cA[offA[h][1]];
            bf16x8 b0 = *(const bf16x8*)&cB[offB[h][0]];
            bf16x8 b1 = *(const bf16x8*)&cB[offB[h][1]];
            acc[0][0] = MFMA16(a0, b0, acc[0][0]);
            acc[0][1] = MFMA16(a0, b1, acc[0][1]);
            acc[1][0] = MFMA16(a1, b0, acc[1][0]);
            acc[1][1] = MFMA16(a1, b1, acc[1][1]);
        }
    }
    // C/D layout: col = lane&15, row = (lane>>4)*4 + reg   [verified m89/m91]
    #pragma unroll
    for (int im = 0; im < 2; im++)
        #pragma unroll
        for (int rr = 0; rr < 4; rr++) {
            int gm = m0C + wr + im * 16 + cb * 4 + rr;
            #pragma unroll
            for (int in_ = 0; in_ < 2; in_++) {
                int cg = n0C + wc + in_ * 16 + fm;
                float v = acc[im][in_][rr];
                if (bias) v += bias[cg];
                if (relu) v = fmaxf(v, 0.f);
                if (Dbf) Dbf[(size_t)gm * Nc + cg] = (bf16_t)v;
                else     Cf[(size_t)gm * Nc + cg] = v;
            }
        }
}

// ---------------- wave-per-row L2 norm of a VCb row ---------------------------
__device__ __forceinline__ void rownorm_row(const bf16_t* __restrict__ VCb,
                                            float* __restrict__ VN, int r, int tid)
{
    const int lane = tid & 63;
    const bf16_t* x = VCb + ((size_t)r << 10) + lane * 16;
    bf16x8 v0 = *(const bf16x8*)x, v1 = *(const bf16x8*)(x + 8);
    float s = 0.f;
    #pragma unroll
    for (int e = 0; e < 8; e++) {
        float a = (float)v0[e], b = (float)v1[e];
        s += a * a + b * b;
    }
    #pragma unroll
    for (int o = 32; o; o >>= 1) s += __shfl_xor(s, o, 64);
    if (lane == 0) VN[r] = sqrtf(s);
}

// -- per-(i, stacked-col) sim: atomic SC accumulate + direct posmap write ------
__device__ __forceinline__ void sim_compute(
    int i, int c, const float* __restrict__ CPat, const float* __restrict__ VN,
    const float* Gs, const float* msk,
    float* __restrict__ SC, float* __restrict__ out)
{
    float s[20], p[20];
    float mx = -1e30f;
    #pragma unroll
    for (int w = 0; w < 20; w++) {
        s[w] = CPat[(size_t)(i * 20 + w) * 1344 + c];
        if (msk[w] != 0.f) mx = fmaxf(mx, s[w]);
    }
    float denom = 0.f, num = 0.f;
    #pragma unroll
    for (int w = 0; w < 20; w++) {
        p[w] = (msk[w] != 0.f) ? __expf(s[w] - mx) : 0.f;
        denom += p[w];
        num   += p[w] * s[w];
    }
    float quad = 0.f;
    #pragma unroll
    for (int w = 0; w < 20; w++) {
        float cc = 0.f;
        #pragma unroll
        for (int w2 = 0; w2 < 20; w2++) cc += Gs[w * 20 + w2] * p[w2];
        quad += p[w] * cc;
    }
    float dot = num / denom;
    float vsn = sqrtf(fmaxf(quad, 0.f)) / denom;
    float sim = dot / (fmaxf(VN[c], 1e-8f) * fmaxf(vsn, 1e-8f));
    int j, t;
    if (c < 1024)      { j = c >> 4;          t = c & 15; }
    else if (c < 1280) { j = (c - 1024) >> 2; t = 16 + ((c - 1024) & 3); }
    else               { j = c - 1280;        t = 20; }
    atomicAdd(SC + i * 64 + j, sim * (1.0f / 21.0f));
    if (i == j) out[1 + i * 21 + t] = sim;
}

// ================= K1: WT0 LDS-transpose + video cast =========================
__global__ __launch_bounds__(256) void prep0_kernel(
    const float* __restrict__ c0w, bf16_t* __restrict__ WT0,
    const float* __restrict__ video, bf16_t* __restrict__ Vb)
{
    __shared__ __align__(16) bf16_t lds[16384];
    int bx = blockIdx.x;
    if (bx < 256) wtrans4(c0w, WT0, bx * 4, threadIdx.x, lds);
    else          cast8(video, Vb, (bx - 256) * 256 + threadIdx.x);
}

// ===== K2: conv0 128x128 GEMM (splitK x4) || WT1/WT2 transposes || casts ======
__global__ __launch_bounds__(256) void d2_kernel(
    const bf16_t* __restrict__ Vb, const bf16_t* __restrict__ WT0, float* __restrict__ CP0,
    const float* __restrict__ c1w, const float* __restrict__ c2w,
    bf16_t* __restrict__ WT1, bf16_t* __restrict__ WT2,
    const float* __restrict__ words, bf16_t* __restrict__ Wordsb,
    const float* __restrict__ c1dw, bf16_t* __restrict__ C1b,
    const float* __restrict__ fcw, bf16_t* __restrict__ Fb)
{
    __shared__ __align__(16) bf16_t smem[32768];   // 64KB
    const int bx = blockIdx.x, tid = threadIdx.x;
    if (bx < 256) {
        // 128x128 tile, 4 waves of 64x64, BK=64, dbuf; splitK x4 (Kchunk 1024)
        bf16_t* sA = smem;            // 2 x 8192
        bf16_t* sB = smem + 16384;    // 2 x 8192
        const int z = bx >> 6, rem = bx & 63, xt = rem & 7, yt = rem >> 3;
        const int m0 = xt * 128, n0 = yt * 128, k0 = z * 1024;
        const int lane = tid & 63, wave = tid >> 6;
        const int sr = tid >> 3, pc = tid & 7, lc = pc ^ (sr & 7);
        const bf16_t* Ag = Vb  + (size_t)(m0 + sr) * 4096 + k0 + lc * 8;
        const bf16_t* Bg = WT0 + (size_t)(n0 + sr) * 4096 + k0 + lc * 8;
        const size_t rowskip = (size_t)32 * 4096;
        const int wrow = (wave >> 1) * 64, wcol = (wave & 1) * 64;
        const int fm = lane & 15, cb = lane >> 4;
        int offA[2][4], offB[2][4];
        #pragma unroll
        for (int h = 0; h < 2; h++)
            #pragma unroll
            for (int m = 0; m < 4; m++) {
                offA[h][m] = swz(wrow + m * 16 + fm, cb + h * 4);
                offB[h][m] = swz(wcol + m * 16 + fm, cb + h * 4);
            }
        f32x4 acc[4][4];
        #pragma unroll
        for (int m = 0; m < 4; m++)
            #pragma unroll
            for (int n = 0; n < 4; n++) acc[m][n] = (f32x4){0.f, 0.f, 0.f, 0.f};

        #pragma unroll
        for (int g = 0; g < 4; g++) {
            gload_lds16(Ag + g * rowskip, &sA[tid * 8 + g * 2048]);
            gload_lds16(Bg + g * rowskip, &sB[tid * 8 + g * 2048]);
        }
        for (int it = 0; it < 16; ++it) {
            const int buf = it & 1;
            __syncthreads();
            if (it < 15) {
                const bf16_t* a = Ag + (it + 1) * 64;
                const bf16_t* b = Bg + (it + 1) * 64;
                #pragma unroll
                for (int g = 0; g < 4; g++) {
                    gload_lds16(a + g * rowskip, &sA[(buf ^ 1) * 8192 + tid * 8 + g * 2048]);
                    gload_lds16(b + g * rowskip, &sB[(buf ^ 1) * 8192 + tid * 8 + g * 2048]);
                }
            }
            #pragma unroll
            for (int h = 0; h < 2; h++) {
                bf16x8 av[4], bv[4];
                #pragma unroll
                for (int m = 0; m < 4; m++) {
                    av[m] = *(const bf16x8*)&sA[buf * 8192 + offA[h][m]];
                    bv[m] = *(const bf16x8*)&sB[buf * 8192 + offB[h][m]];
                }
                #pragma unroll
                for (int m = 0; m < 4; m++)
                    #pragma unroll
                    for (int n = 0; n < 4; n++)
                        acc[m][n] = MFMA16(av[m], bv[n], acc[m][n]);
            }
        }
        float* Cz = CP0 + (size_t)z * CP0_SL;
        #pragma unroll
        for (int m = 0; m < 4; m++)
            #pragma unroll
            for (int rr = 0; rr < 4; rr++) {
                int gm = m0 + wrow + m * 16 + cb * 4 + rr;
                #pragma unroll
                for (int n = 0; n < 4; n++) {
                    int cg = n0 + wcol + n * 16 + fm;
                    Cz[(size_t)gm * 1024 + cg] = acc[m][n][rr];
                }
            }
    } else if (bx < 768) {                  // WT1/WT2 LDS transposes
        int b2 = bx - 256;
        if (b2 < 256) wtrans4(c1w, WT1, b2 * 4, tid, smem);
        else          wtrans4(c2w, WT2, (b2 - 256) * 4, tid, smem);
    } else {                                // words / conv1d_w / fc_w casts
        int b2 = bx - 768;
        if (b2 < 640)       cast8(words, Wordsb, b2 * 256 + tid);
        else if (b2 < 1152) cast8(c1dw, C1b, (b2 - 640) * 256 + tid);
        else                cast8(fcw, Fb, (b2 - 1152) * 256 + tid);
    }
}

// == K3: conv0 epilogue || word gram (wave-per-pair) || SC zero-init ===========
__global__ __launch_bounds__(256) void d3_kernel(
    const float* __restrict__ CP0, const float* __restrict__ c0b,
    bf16_t* __restrict__ Astack, const bf16_t* __restrict__ Wordsb,
    float* __restrict__ GR, float* __restrict__ SC)
{
    int bx = blockIdx.x, tid = threadIdx.x;
    if (bx < 512) {
        int idx8 = bx * 256 + tid;          // < 131072 ; 8 elems each
        size_t base = (size_t)idx8 * 8;
        int nb = (int)(base & 1023);
        f32x4 s0 = *(const f32x4*)(c0b + nb);
        f32x4 s1 = *(const f32x4*)(c0b + nb + 4);
        #pragma unroll
        for (int z = 0; z < 4; z++) {
            const float* p = CP0 + (size_t)z * CP0_SL + base;
            s0 += *(const f32x4*)p;
            s1 += *(const f32x4*)(p + 4);
        }
        bf16x8 o;
        #pragma unroll
        for (int e = 0; e < 4; e++) {
            o[e]     = (bf16_t)fmaxf(s0[e], 0.f);
            o[4 + e] = (bf16_t)fmaxf(s1[e], 0.f);
        }
        *(bf16x8*)(Astack + base) = o;
    } else if (bx < 6912) {
        // gram: one wave per (i, w, w2) pair; rows read from L2-resident Wordsb
        int g = bx - 512;                   // 0..6399
        int i = g / 100, piece = g % 100;
        int wave = tid >> 6, lane = tid & 63;
        int pair = piece * 4 + wave;        // 0..399 = w*20+w2
        int w = pair / 20, w2 = pair % 20;
        const bf16_t* a = Wordsb + (((size_t)i * 20 + w)  << 10) + lane * 16;
        const bf16_t* b = Wordsb + (((size_t)i * 20 + w2) << 10) + lane * 16;
        bf16x8 a0 = *(const bf16x8*)a, a1 = *(const bf16x8*)(a + 8);
        bf16x8 b0 = *(const bf16x8*)b, b1 = *(const bf16x8*)(b + 8);
        float s = 0.f;
        #pragma unroll
        for (int e = 0; e < 8; e++)
            s += (float)a0[e] * (float)b0[e] + (float)a1[e] * (float)b1[e];
        #pragma unroll
        for (int o = 32; o; o >>= 1) s += __shfl_xor(s, o, 64);
        if (lane == 0) GR[(size_t)i * 400 + pair] = s;
    } else {                                // SC zero-init (4096 floats)
        int idx = (bx - 6912) * 1024 + tid * 4;
        *(f32x4*)(SC + idx) = (f32x4){0.f, 0.f, 0.f, 0.f};
    }
}

// == K4: conv1 splitK1 (bias+relu -> A2b) || c1d0 -> VCb rows 0..1023 ==========
__global__ __launch_bounds__(256) void d4_kernel(
    const bf16_t* __restrict__ Astack, const bf16_t* __restrict__ WT1,
    const float* __restrict__ c1b, bf16_t* __restrict__ A2b,
    const bf16_t* __restrict__ C1b, const float* __restrict__ c1db,
    bf16_t* __restrict__ VCb)
{
    __shared__ __align__(16) bf16_t smem[32768];
    bf16_t* sA = smem; bf16_t* sB = smem + 16384;
    int bx = blockIdx.x;
    if (bx < 64) {           // conv1: M=256 N=1024 K=4096, splitK1, relu
        int xt = bx & 3, yt = bx >> 2;
        gemm64(Astack, WT1, 1024, 4096, xt * 64, yt * 64, 0, 32,
               xt * 64, yt * 64, sA, sB, nullptr, c1b, A2b, 1);
    } else {                 // c1d0: M=1024 N=1024 K=1024, splitK1 + bias
        int b2 = bx - 64;    // 0..255
        int xt = b2 & 15, yt = b2 >> 4;
        gemm64(Astack, C1b, 1024, 1024, xt * 64, yt * 64, 0, 8,
               xt * 64, yt * 64, sA, sB, nullptr, c1db, VCb, 0);
    }
}

// == K5: conv2 splitK1 (bias+relu -> A3b) || c1d1 || attn cols<1024 || rn0 =====
__global__ __launch_bounds__(256) void d6_kernel(
    const bf16_t* __restrict__ A2b, const bf16_t* __restrict__ WT2,
    const float* __restrict__ c2b, bf16_t* __restrict__ A3b,
    const bf16_t* __restrict__ C1b, const float* __restrict__ c1db,
    const bf16_t* __restrict__ Wordsb, bf16_t* __restrict__ VCb,
    float* __restrict__ CPat, float* __restrict__ VN)
{
    __shared__ __align__(16) bf16_t smem[32768];
    bf16_t* sA = smem; bf16_t* sB = smem + 16384;
    int bx = blockIdx.x, tid = threadIdx.x;
    if (bx < 16) {           // conv2: M=64 N=1024 K=4096, splitK1, relu
        gemm64(A2b, WT2, 1024, 4096, 0, bx * 64, 0, 32,
               0, bx * 64, sA, sB, nullptr, c2b, A3b, 1);
    } else if (bx < 336) {   // attn0: M=1280, cols 0..1023, K=1024
        int g = bx - 16;                    // 0..319
        int xt = g % 20, yt = g / 20;
        gemm64(Wordsb, VCb, 1344, 1024, xt * 64, yt * 64, 0, 8,
               xt * 64, yt * 64, sA, sB, CPat, nullptr, nullptr, 0);
    } else if (bx < 400) {   // c1d1: M=256 N=1024 K=1024 -> VCb rows 1024..1279
        int g = bx - 336;
        int xt = g & 3, yt = g >> 2;
        gemm64(A2b, C1b, 1024, 1024, xt * 64, yt * 64, 0, 8,
               1024 + xt * 64, yt * 64, sA, sB, nullptr, c1db, VCb, 0);
    } else {                 // rownorm rows 0..1023
        int r = (bx - 400) * 4 + (tid >> 6);
        rownorm_row(VCb, VN, r, tid);
    }
}

// == K6: c1d2+fc from A3b || attn cols 1024..1279 || sim0 || rn-mid ============
__global__ __launch_bounds__(256) void d7_kernel(
    const bf16_t* __restrict__ A3b, const bf16_t* __restrict__ C1b,
    const bf16_t* __restrict__ Fb,
    const float* __restrict__ c1db, const float* __restrict__ fcb,
    bf16_t* __restrict__ VCb, float* __restrict__ GV,
    const bf16_t* __restrict__ Wordsb, float* __restrict__ CPat,
    const float* __restrict__ GR, float* __restrict__ VN,
    const int* __restrict__ wmask, float* __restrict__ SC, float* __restrict__ out)
{
    __shared__ __align__(16) bf16_t smem[32768];   // 64KB
    bf16_t* sA = smem; bf16_t* sB = smem + 16384;
    const int bx = blockIdx.x, tid = threadIdx.x;
    if (bx < 16) {           // c1d2: M=64 N=1024 K=1024 -> VCb rows 1280..1343
        gemm64(A3b, C1b, 1024, 1024, 0, bx * 64, 0, 8,
               1280, bx * 64, sA, sB, nullptr, c1db, VCb, 0);
    } else if (bx < 32) {    // fc: M=64 N=1024 K=1024 -> GV (f32 + bias)
        int yt = bx - 16;
        gemm64(A3b, Fb, 1024, 1024, 0, yt * 64, 0, 8,
               0, yt * 64, sA, sB, GV, fcb, nullptr, 0);
    } else if (bx < 112) {   // attn1: cols 1024..1279
        int g = bx - 32;                    // 0..79
        int xt = g % 20, yt = g / 20;
        gemm64(Wordsb, VCb, 1344, 1024, xt * 64, 1024 + yt * 64, 0, 8,
               xt * 64, 1024 + yt * 64, sA, sB, CPat, nullptr, nullptr, 0);
    } else if (bx < 368) {   // sim for stacked cols 0..1023
        int s = bx - 112;                   // 0..255
        int i = s >> 2, seg = s & 3;
        float* Gs  = (float*)smem;
        float* msk = Gs + 400;
        for (int q = tid; q < 400; q += 256) Gs[q] = GR[(size_t)i * 400 + q];
        if (tid < 20) msk[tid] = (wmask[i * 20 + tid] != 0) ? 1.f : 0.f;
        __syncthreads();
        sim_compute(i, seg * 256 + tid, CPat, VN, Gs, msk, SC, out);
    } else {                 // rownorm rows 1024..1279
        int r = 1024 + (bx - 368) * 4 + (tid >> 6);
        rownorm_row(VCb, VN, r, tid);
    }
}

// = K7: attn cols 1280.. || rownorm 1280.. || gscore || sim cols 1024..1279 ====
__global__ __launch_bounds__(256) void d8_kernel(
    const bf16_t* __restrict__ Wordsb, const bf16_t* __restrict__ VCb,
    float* __restrict__ CPat, float* __restrict__ VN,
    const float* __restrict__ sent, const float* __restrict__ GV,
    float* __restrict__ GS, const float* __restrict__ GR,
    const int* __restrict__ wmask, float* __restrict__ SC, float* __restrict__ out)
{
    __shared__ __align__(16) bf16_t smem[32768];
    bf16_t* sA = smem; bf16_t* sB = smem + 16384;
    int bx = blockIdx.x, tid = threadIdx.x;
    if (bx < 20) {           // attn2
        gemm64(Wordsb, VCb, 1344, 1024, bx * 64, 1280, 0, 8,
               bx * 64, 1280, sA, sB, CPat, nullptr, nullptr, 0);
    } else if (bx < 36) {    // rownorm rows 1280..1343
        int r = 1280 + (bx - 20) * 4 + (tid >> 6);
        rownorm_row(VCb, VN, r, tid);
    } else if (bx < 1060) {  // gscore (cosine of sentences vs GV)
        int item = (bx - 36) * 4 + (tid >> 6);
        int i = item >> 6, j = item & 63;
        int lane = tid & 63;
        const float* a = sent + (size_t)i * 1024;
        const float* b = GV + (size_t)j * 1024;
        float sab = 0.f, saa = 0.f, sbb = 0.f;
        #pragma unroll
        for (int q = 0; q < 16; q++) {
            int d = lane + 64 * q;
            float av = a[d], bv = b[d];
            sab += av * bv; saa += av * av; sbb += bv * bv;
        }
        #pragma unroll
        for (int o = 32; o; o >>= 1) {
            sab += __shfl_xor(sab, o, 64);
            saa += __shfl_xor(saa, o, 64);
            sbb += __shfl_xor(sbb, o, 64);
        }
        if (lane == 0)
            GS[item] = sab / (fmaxf(sqrtf(saa), 1e-8f) * fmaxf(sqrtf(sbb), 1e-8f));
    } else {                 // sim cols 1024..1279
        int i = bx - 1060;
        float* Gs  = (float*)smem;
        float* msk = Gs + 400;
        for (int q = tid; q < 400; q += 256) Gs[q] = GR[(size_t)i * 400 + q];
        if (tid < 20) msk[tid] = (wmask[i * 20 + tid] != 0) ? 1.f : 0.f;
        __syncthreads();
        sim_compute(i, 1024 + tid, CPat, VN, Gs, msk, SC, out);
    }
}

// ================= K8: sim cols 1280..1343 ====================================
__global__ __launch_bounds__(256) void d9_kernel(
    const float* __restrict__ CPat, const float* __restrict__ GR,
    const float* __restrict__ VN, const int* __restrict__ wmask,
    float* __restrict__ SC, float* __restrict__ out)
{
    __shared__ float Gs[400];
    __shared__ float msk[20];
    int i = blockIdx.x, tid = threadIdx.x;
    for (int q = tid; q < 400; q += 256) Gs[q] = GR[(size_t)i * 400 + q];
    if (tid < 20) msk[tid] = (wmask[i * 20 + tid] != 0) ? 1.f : 0.f;
    __syncthreads();
    if (tid < 64) sim_compute(i, 1280 + tid, CPat, VN, Gs, msk, SC, out);
}

// ================= K9: margin ranking loss ====================================
__global__ __launch_bounds__(256) void loss_kernel(
    const float* __restrict__ SC_, const float* __restrict__ GS_,
    float* __restrict__ out)
{
    __shared__ float d1[64], d2[64], red[4];
    int tid = threadIdx.x;
    if (tid < 64) { d1[tid] = SC_[tid * 65]; d2[tid] = GS_[tid * 65]; }
    __syncthreads();
    float acc = 0.f;
    for (int idx = tid; idx < 4096; idx += 256) {
        int i = idx >> 6, j = idx & 63;
        if (i != j) {
            float s = SC_[idx];
            acc += fmaxf(0.2f + s - d1[i], 0.f) + fmaxf(0.2f + s - d1[j], 0.f);
            float g = GS_[idx];
            acc += fmaxf(0.2f + g - d2[i], 0.f) + fmaxf(0.2f + g - d2[j], 0.f);
        }
    }
    #pragma unroll
    for (int o = 32; o; o >>= 1) acc += __shfl_xor(acc, o, 64);
    if ((tid & 63) == 0) red[tid >> 6] = acc;
    __syncthreads();
    if (tid == 0) out[0] = (red[0] + red[1] + red[2] + red[3]) * (1.0f / 64.0f);
}

// ------------------------------------------------------------------------------
extern "C" void kernel_launch(void* const* d_in, const int* in_sizes, int n_in,
                              void* d_out, int out_size, void* d_ws, size_t ws_size,
                              hipStream_t stream)
{
    const float* video     = (const float*)d_in[0];
    const float* words     = (const float*)d_in[1];
    const int*   w_masks   = (const int*)  d_in[2];
    const float* sentences = (const float*)d_in[3];
    const float* conv0_w   = (const float*)d_in[4];
    const float* conv0_b   = (const float*)d_in[5];
    const float* conv1_w   = (const float*)d_in[6];
    const float* conv1_b   = (const float*)d_in[7];
    const float* conv2_w   = (const float*)d_in[8];
    const float* conv2_b   = (const float*)d_in[9];
    const float* conv1d_w  = (const float*)d_in[10];
    const float* conv1d_b  = (const float*)d_in[11];
    const float* fc_w      = (const float*)d_in[12];
    const float* fc_b      = (const float*)d_in[13];
    float* out = (float*)d_out;
    float* ws = (float*)d_ws;

    // ---- flat workspace (float units) ----------------------------------------
    bf16_t* WT0    = (bf16_t*)(ws + 0);            // 1024x4096 bf16
    bf16_t* WT1    = (bf16_t*)(ws + 2097152);
    bf16_t* WT2    = (bf16_t*)(ws + 4194304);
    bf16_t* Vb     = (bf16_t*)(ws + 6291456);      // 4096x1024 bf16
    bf16_t* Wordsb = (bf16_t*)(ws + 8388608);      // 1,310,720 bf16
    bf16_t* C1b    = (bf16_t*)(ws + 9043968);      // 1,048,576 bf16
    bf16_t* Fb     = (bf16_t*)(ws + 9568256);      // 1,048,576 bf16
    bf16_t* Astack = (bf16_t*)(ws + 10092544);     // 1024x1024 bf16 (conv0 out)
    bf16_t* A2b    = (bf16_t*)(ws + 10616832);     // 256x1024 bf16 (conv1 out)
    bf16_t* A3b    = (bf16_t*)(ws + 10747904);     // 64x1024 bf16 (conv2 out)
    bf16_t* VCb    = (bf16_t*)(ws + 10780672);     // 1344x1024 bf16 (STACKED)
    float*  CP0    = ws + 11468800;                // 4 x 1,048,576 f
    float*  CPat   = ws + 15663104;                // 1,720,320 f (single slice)
    float*  VN     = ws + 17383424;                // 1,344
    float*  GR     = ws + 17384768;                // 25,600
    float*  SC     = ws + 17410368;                // 4,096
    float*  GV     = ws + 17414464;                // 65,536
    float*  GS     = ws + 17480000;                // 4,096 (ends 17,484,096)

    dim3 blk(256);

    // K1: WT0 transpose + video cast
    prep0_kernel<<<2304, blk, 0, stream>>>(conv0_w, WT0, video, Vb);
    // K2: conv0 GEMM || WT1/WT2 transposes || casts
    d2_kernel<<<2432, blk, 0, stream>>>(Vb, WT0, CP0, conv1_w, conv2_w, WT1, WT2,
                                        words, Wordsb, conv1d_w, C1b, fc_w, Fb);
    // K3: conv0 epi || gram || SC zero
    d3_kernel<<<6916, blk, 0, stream>>>(CP0, conv0_b, Astack, Wordsb, GR, SC);
    // K4: conv1 (splitK1, fused) || c1d0 -> VCb[0..1024)
    d4_kernel<<<320, blk, 0, stream>>>(Astack, WT1, conv1_b, A2b, C1b, conv1d_b, VCb);
    // K5: conv2 (splitK1, fused) || attn0 || c1d1 -> VCb[1024..1280) || rownorm0
    d6_kernel<<<656, blk, 0, stream>>>(A2b, WT2, conv2_b, A3b, C1b, conv1d_b,
                                       Wordsb, VCb, CPat, VN);
    // K6: c1d2+fc from A3b || attn1 || sim0 || rownorm-mid
    d7_kernel<<<432, blk, 0, stream>>>(A3b, C1b, Fb, conv1d_b, fc_b,
                                       VCb, GV, Wordsb, CPat, GR, VN, w_masks, SC, out);
    // K7: attn2 || rownorm-hi || gscore || sim-mid
    d8_kernel<<<1124, blk, 0, stream>>>(Wordsb, VCb, CPat, VN, sentences, GV, GS,
                                        GR, w_masks, SC, out);
    // K8: sim tail
    d9_kernel<<<64, blk, 0, stream>>>(CPat, GR, VN, w_masks, SC, out);
    // K9: loss
    loss_kernel<<<1, blk, 0, stream>>>(SC, GS, out);
}